// Round 5
// baseline (1445.056 us; speedup 1.0000x reference)
//
#include <hip/hip_runtime.h>
#include <math.h>

// Problem constants
constexpr int kB   = 2;
constexpr int kF   = 257;   // FQ
constexpr int kT   = 100;
constexpr int kH   = 96;
constexpr int kS   = 8;
constexpr int kD   = 192;   // DIN
constexpr int kN   = 16;
constexpr int kR   = 6;
constexpr int kKF  = 5;
constexpr int kKM  = 4;
constexpr int kG   = 8;     // GROUPS
constexpr int kGC  = kH / kG;        // 12
constexpr int kBM  = kB * kF;        // 514
constexpr int kROWS = kB * kF * kT;  // 51400
constexpr int kNX  = kROWS * kH;     // 4,934,400
constexpr int kNM  = kROWS * kD;     // 9,868,800
constexpr int kDBL = kR + 2 * kN;    // 38
constexpr int kDBLP = 48;            // padded

__device__ inline float wave_reduce_sum(float v) {
    for (int o = 32; o > 0; o >>= 1) v += __shfl_xor(v, o, 64);
    return v;
}
__device__ inline float silu_f(float x) { return x / (1.f + __expf(-x)); }
__device__ inline float softplus_f(float x) { return x > 20.f ? x : log1pf(__expf(x)); }

// ---------------- LayerNorm over H=96, one wave per row ----------------
__global__ void ln_kernel(const float* __restrict__ in, float* __restrict__ out,
                          const float* __restrict__ g, const float* __restrict__ b,
                          int rows) {
    int wave = threadIdx.x >> 6;
    int lane = threadIdx.x & 63;
    int r = blockIdx.x * 4 + wave;
    if (r >= rows) return;
    const float* p = in + (size_t)r * kH;
    float v0 = p[lane];
    float v1 = (lane < 32) ? p[64 + lane] : 0.f;
    float s = wave_reduce_sum(v0 + v1);
    float mean = s * (1.f / 96.f);
    float d0 = v0 - mean;
    float d1 = (lane < 32) ? (v1 - mean) : 0.f;
    float vs = wave_reduce_sum(d0 * d0 + d1 * d1);
    float rstd = rsqrtf(vs * (1.f / 96.f) + 1e-5f);
    float* q = out + (size_t)r * kH;
    q[lane] = d0 * rstd * g[lane] + b[lane];
    if (lane < 32) q[64 + lane] = d1 * rstd * g[64 + lane] + b[64 + lane];
}

// ---------------- freq-conv stage ----------------
#define FDOT(S,K) \
  acc += xw[S][0].x*wr[K][0] + xw[S][0].y*wr[K][1] + xw[S][0].z*wr[K][2] + xw[S][0].w*wr[K][3] \
       + xw[S][1].x*wr[K][4] + xw[S][1].y*wr[K][5] + xw[S][1].z*wr[K][6] + xw[S][1].w*wr[K][7] \
       + xw[S][2].x*wr[K][8] + xw[S][2].y*wr[K][9] + xw[S][2].z*wr[K][10]+ xw[S][2].w*wr[K][11];

#define FSTEP(S0,S1,S2,S3,S4)                                              \
  if (f < fmax) {                                                          \
    const float4* cp = (const float4*)(Xs + (f + 4) * 12);                 \
    xw[S4][0] = cp[0]; xw[S4][1] = cp[1]; xw[S4][2] = cp[2];               \
    float acc = bias;                                                      \
    FDOT(S0,0) FDOT(S1,1) FDOT(S2,2) FDOT(S3,3) FDOT(S4,4)                 \
    float yv = acc > 0.f ? acc : alpha_h * acc;                            \
    size_t oi = ((size_t)(bb * kF + f) * kT + tt) * kH + g12 + hh;         \
    out[oi] = resid[oi] + yv;                                              \
    f++;                                                                   \
  }

__global__ __launch_bounds__(256)
void fconv_kernel(const float* __restrict__ ln, const float* __restrict__ resid,
                  float* __restrict__ out, const float* __restrict__ w,
                  const float* __restrict__ cb, const float* __restrict__ alpha) {
    __shared__ float Xs[261 * 12];
    __shared__ float Ws[kGC * kKF * 12];  // 720
    int g = blockIdx.x, tt = blockIdx.y, bb = blockIdx.z;
    int g12 = g * 12;
    int tid = threadIdx.x;

    for (int i = tid; i < 720; i += 256) Ws[i] = w[g * 720 + i];
    for (int i = tid; i < 257 * 12; i += 256) {
        int fs = i / 12, ci = i - fs * 12;
        Xs[(fs + 2) * 12 + ci] = ln[((size_t)(bb * kF + fs) * kT + tt) * kH + g12 + ci];
    }
    if (tid < 48) {
        const int padr[4] = {0, 1, 259, 260};
        Xs[padr[tid / 12] * 12 + (tid % 12)] = 0.f;
    }
    __syncthreads();

    int lane = tid & 63, wave = tid >> 6;
    int hh = lane % 12, fi = lane / 12;
    if (fi >= 5) return;                      // duplicate-slot lanes must retire (in-place race)
    int slot = wave * 5 + fi;
    int f0 = slot * 13;
    int fmax = min(f0 + 13, kF);

    float wr[5][12];
    #pragma unroll
    for (int k = 0; k < 5; k++)
        #pragma unroll
        for (int ci = 0; ci < 12; ci++)
            wr[k][ci] = Ws[hh * 60 + ci * 5 + k];

    float bias = cb[g12 + hh];
    float alpha_h = alpha[g12 + hh];

    float4 xw[5][3];
    #pragma unroll
    for (int s = 0; s < 4; s++) {
        int row = min(f0 + s, 260);
        const float4* cp = (const float4*)(Xs + row * 12);
        xw[s][0] = cp[0]; xw[s][1] = cp[1]; xw[s][2] = cp[2];
    }
    int f = f0;
    for (int rep = 0; rep < 3; rep++) {
        FSTEP(0,1,2,3,4)
        FSTEP(1,2,3,4,0)
        FSTEP(2,3,4,0,1)
        FSTEP(3,4,0,1,2)
        FSTEP(4,0,1,2,3)
    }
}

// ---------------- full stage: squeeze H->S with SiLU ----------------
__global__ void squeeze_kernel(const float* __restrict__ ln, float* __restrict__ s1,
                               const float* __restrict__ sqw, const float* __restrict__ sqb) {
    int bt = blockIdx.x;                       // b*kT + t
    int f = blockIdx.y * 64 + threadIdx.x;
    if (f >= kF) return;
    int b = bt / kT, t = bt % kT;
    const float* row = ln + ((size_t)(b * kF + f) * kT + t) * kH;
    float acc[kS];
    for (int s = 0; s < kS; s++) acc[s] = 0.f;
    for (int h = 0; h < kH; h++) {
        float v = row[h];
        for (int s = 0; s < kS; s++) acc[s] += v * sqw[s * kH + h];
    }
    for (int s = 0; s < kS; s++)
        s1[((size_t)bt * kS + s) * kF + f] = silu_f(acc[s] + sqb[s]);
}

// ---------------- full stage: per-group GEMM over F ----------------
__global__ __launch_bounds__(256)
void fullmat_gemm(const float* __restrict__ s1, float* __restrict__ s2,
                  const float* __restrict__ fw, const float* __restrict__ fb) {
    __shared__ float As[64 * 64];  // [fk][bt]
    __shared__ float Bs[64 * 64];  // [fk][k]
    int k0 = blockIdx.x * 64, bt0 = blockIdx.y * 64, g = blockIdx.z;
    int tid = threadIdx.x;
    int rt = tid >> 4, ct = tid & 15;
    float acc[4][4];
    #pragma unroll
    for (int i = 0; i < 4; i++)
        #pragma unroll
        for (int j = 0; j < 4; j++) acc[i][j] = 0.f;

    for (int f0 = 0; f0 < kF; f0 += 64) {
        int fcnt = min(64, kF - f0);
        for (int i = tid; i < 64 * 64; i += 256) {
            int m = i & 63, fk = i >> 6;
            int bt = bt0 + m, f = f0 + fk;
            As[fk * 64 + m] = (bt < kB * kT && f < kF)
                ? s1[((size_t)bt * kS + g) * kF + f] : 0.f;
            int k = k0 + m;
            Bs[fk * 64 + m] = (k < kF && f < kF)
                ? fw[(size_t)g * kF * kF + (size_t)k * kF + f] : 0.f;
        }
        __syncthreads();
        for (int f = 0; f < fcnt; f++) {
            float4 a4 = *(const float4*)&As[f * 64 + rt * 4];
            float4 b4 = *(const float4*)&Bs[f * 64 + ct * 4];
            float ar[4] = {a4.x, a4.y, a4.z, a4.w};
            float br[4] = {b4.x, b4.y, b4.z, b4.w};
            #pragma unroll
            for (int i = 0; i < 4; i++)
                #pragma unroll
                for (int j = 0; j < 4; j++) acc[i][j] += ar[i] * br[j];
        }
        __syncthreads();
    }
    #pragma unroll
    for (int i = 0; i < 4; i++) {
        int bt = bt0 + rt * 4 + i;
        if (bt >= kB * kT) continue;
        #pragma unroll
        for (int j = 0; j < 4; j++) {
            int k = k0 + ct * 4 + j;
            if (k >= kF) continue;
            s2[((size_t)bt * kS + g) * kF + k] = acc[i][j] + fb[g * kF + k];
        }
    }
}

// ---------------- full stage: unsqueeze S->H + SiLU + residual ----------------
__global__ void unsqueeze_kernel(const float* __restrict__ s2, float* __restrict__ x,
                                 const float* __restrict__ uw, const float* __restrict__ ub) {
    int idx = blockIdx.x * blockDim.x + threadIdx.x;
    if (idx >= kNX) return;
    int h = idx % kH;
    int t = (idx / kH) % kT;
    int f = (idx / (kH * kT)) % kF;
    int b = idx / (kH * kT * kF);
    int bt = b * kT + t;
    float acc = ub[h];
    for (int s = 0; s < kS; s++)
        acc += s2[((size_t)bt * kS + s) * kF + f] * uw[h * kS + s];
    x[idx] += silu_f(acc);
}

// ---------------- small weight transpose ----------------
__global__ void transpose_kernel(const float* __restrict__ in, float* __restrict__ out,
                                 int rows, int cols) {
    int idx = blockIdx.x * blockDim.x + threadIdx.x;
    if (idx >= rows * cols) return;
    int r = idx / cols, c = idx % cols;
    out[c * rows + r] = in[idx];
}

// out_w [96][192] -> padded transpose wp [192][128] (cols >=96 zero)
__global__ void outpad_kernel(const float* __restrict__ w, float* __restrict__ wp) {
    int i = blockIdx.x * 256 + threadIdx.x;
    if (i >= kD * 128) return;
    int d = i >> 7, h = i & 127;
    wp[i] = (h < kH) ? w[h * kD + d] : 0.f;
}

// xp_w [38][192] -> padded transpose wpx [192][48] (cols >=38 zero)
__global__ void xppad_kernel(const float* __restrict__ w, float* __restrict__ wp) {
    int i = blockIdx.x * 256 + threadIdx.x;
    if (i >= kD * kDBLP) return;
    int d = i / kDBLP, n = i % kDBLP;
    wp[i] = (n < kDBL) ? w[n * kD + d] : 0.f;
}

// ---------------- mamba in-proj GEMM: [51400x96] @ [96x384] ----------------
__global__ __launch_bounds__(128)
void inproj_gemm(const float* __restrict__ xn, const float* __restrict__ wT,
                 float* __restrict__ xin, float* __restrict__ z) {
    __shared__ float Al[96 * 64];
    int r0 = blockIdx.x * 64;
    int c0 = blockIdx.y * 128;
    int tid = threadIdx.x;
    for (int i = tid; i < 96 * 64; i += 128) {
        int m = i & 63, h = i >> 6;
        int r = r0 + m; if (r >= kROWS) r = kROWS - 1;
        Al[h * 64 + m] = xn[(size_t)r * kH + h];
    }
    __syncthreads();
    int rt = tid >> 4, ct = tid & 15;
    const float* bp = wT + c0 + ct * 8;
    float4 acc[8][2];
    #pragma unroll
    for (int i = 0; i < 8; i++) {
        acc[i][0] = make_float4(0.f, 0.f, 0.f, 0.f);
        acc[i][1] = make_float4(0.f, 0.f, 0.f, 0.f);
    }
    for (int h = 0; h < 96; h++) {
        float4 a0 = *(const float4*)&Al[h * 64 + rt * 8];
        float4 a1 = *(const float4*)&Al[h * 64 + rt * 8 + 4];
        float4 b0 = *(const float4*)&bp[(size_t)h * 384];
        float4 b1 = *(const float4*)&bp[(size_t)h * 384 + 4];
        float ar[8] = {a0.x, a0.y, a0.z, a0.w, a1.x, a1.y, a1.z, a1.w};
        #pragma unroll
        for (int i = 0; i < 8; i++) {
            float av = ar[i];
            acc[i][0].x += av * b0.x; acc[i][0].y += av * b0.y;
            acc[i][0].z += av * b0.z; acc[i][0].w += av * b0.w;
            acc[i][1].x += av * b1.x; acc[i][1].y += av * b1.y;
            acc[i][1].z += av * b1.z; acc[i][1].w += av * b1.w;
        }
    }
    int cbase = c0 + ct * 8;
    #pragma unroll
    for (int i = 0; i < 8; i++) {
        int r = r0 + rt * 8 + i;
        if (r >= kROWS) break;
        if (cbase < kD) {
            *(float4*)&xin[(size_t)r * kD + cbase]     = acc[i][0];
            *(float4*)&xin[(size_t)r * kD + cbase + 4] = acc[i][1];
        } else {
            *(float4*)&z[(size_t)r * kD + cbase - kD]     = acc[i][0];
            *(float4*)&z[(size_t)r * kD + cbase - kD + 4] = acc[i][1];
        }
    }
}

// ---------------- mamba out-proj GEMM + combine: [51400x192] @ [192x128pad] ----------------
__global__ __launch_bounds__(128)
void outproj_gemm(const float* __restrict__ ym, const float* __restrict__ wp,
                  const float* __restrict__ xres, float* __restrict__ out, int dir) {
    __shared__ float Al[192 * 64];  // 48 KiB
    int r0 = blockIdx.x * 64;
    int tid = threadIdx.x;
    for (int i = tid; i < 192 * 64; i += 128) {
        int m = i & 63, h = i >> 6;
        int r = r0 + m; if (r >= kROWS) r = kROWS - 1;
        Al[h * 64 + m] = ym[(size_t)r * kD + h];
    }
    __syncthreads();
    int rt = tid >> 4, ct = tid & 15;
    const float* bp = wp + ct * 8;
    float4 acc[8][2];
    #pragma unroll
    for (int i = 0; i < 8; i++) {
        acc[i][0] = make_float4(0.f, 0.f, 0.f, 0.f);
        acc[i][1] = make_float4(0.f, 0.f, 0.f, 0.f);
    }
    for (int h = 0; h < 192; h++) {
        float4 a0 = *(const float4*)&Al[h * 64 + rt * 8];
        float4 a1 = *(const float4*)&Al[h * 64 + rt * 8 + 4];
        float4 b0 = *(const float4*)&bp[h * 128];
        float4 b1 = *(const float4*)&bp[h * 128 + 4];
        float ar[8] = {a0.x, a0.y, a0.z, a0.w, a1.x, a1.y, a1.z, a1.w};
        #pragma unroll
        for (int i = 0; i < 8; i++) {
            float av = ar[i];
            acc[i][0].x += av * b0.x; acc[i][0].y += av * b0.y;
            acc[i][0].z += av * b0.z; acc[i][0].w += av * b0.w;
            acc[i][1].x += av * b1.x; acc[i][1].y += av * b1.y;
            acc[i][1].z += av * b1.z; acc[i][1].w += av * b1.w;
        }
    }
    int cbase = ct * 8;
    if (cbase >= kH) return;
    #pragma unroll
    for (int i = 0; i < 8; i++) {
        int r = r0 + rt * 8 + i;
        if (r >= kROWS) break;
        float4 v0 = acc[i][0], v1 = acc[i][1];
        size_t o = (size_t)r * kH + cbase;
        if (dir == 0) {
            float4 x0 = *(const float4*)&xres[o], x1 = *(const float4*)&xres[o + 4];
            v0.x = x0.x + 0.5f * v0.x; v0.y = x0.y + 0.5f * v0.y;
            v0.z = x0.z + 0.5f * v0.z; v0.w = x0.w + 0.5f * v0.w;
            v1.x = x1.x + 0.5f * v1.x; v1.y = x1.y + 0.5f * v1.y;
            v1.z = x1.z + 0.5f * v1.z; v1.w = x1.w + 0.5f * v1.w;
        } else {
            float4 x0 = *(const float4*)&out[o], x1 = *(const float4*)&out[o + 4];
            v0.x = x0.x + 0.5f * v0.x; v0.y = x0.y + 0.5f * v0.y;
            v0.z = x0.z + 0.5f * v0.z; v0.w = x0.w + 0.5f * v0.w;
            v1.x = x1.x + 0.5f * v1.x; v1.y = x1.y + 0.5f * v1.y;
            v1.z = x1.z + 0.5f * v1.z; v1.w = x1.w + 0.5f * v1.w;
        }
        *(float4*)&out[o] = v0;
        *(float4*)&out[o + 4] = v1;
    }
}

// ---------------- mamba depthwise conv over T + SiLU ----------------
__global__ void mconv_kernel(const float* __restrict__ xin, float* __restrict__ xc,
                             const float* __restrict__ cw, const float* __restrict__ cb, int dir) {
    int qid = blockIdx.x * blockDim.x + threadIdx.x;
    if (qid >= kROWS * 48) return;
    int r = qid / 48, d4 = (qid - r * 48) * 4;
    int bm = r / kT, t = r - bm * kT;
    float4 acc = make_float4(cb[d4], cb[d4 + 1], cb[d4 + 2], cb[d4 + 3]);
    #pragma unroll
    for (int k = 0; k < kKM; k++) {
        int ts = dir ? (t + 3 - k) : (t + k - 3);
        if (ts < 0 || ts >= kT) continue;
        float4 v = *(const float4*)&xin[((size_t)bm * kT + ts) * kD + d4];
        acc.x += v.x * cw[(d4 + 0) * kKM + k];
        acc.y += v.y * cw[(d4 + 1) * kKM + k];
        acc.z += v.z * cw[(d4 + 2) * kKM + k];
        acc.w += v.w * cw[(d4 + 3) * kKM + k];
    }
    float4 o = make_float4(silu_f(acc.x), silu_f(acc.y), silu_f(acc.z), silu_f(acc.w));
    *(float4*)&xc[(size_t)r * kD + d4] = o;
}

// ---------------- mamba x-proj GEMM: [51400x192] @ [192x48pad] ----------------
__global__ __launch_bounds__(128)
void xpproj_gemm(const float* __restrict__ xc, float* __restrict__ dbl,
                 const float* __restrict__ wpx) {
    __shared__ float Al[192 * 64];  // 48 KiB
    int r0 = blockIdx.x * 64;
    int tid = threadIdx.x;
    for (int i = tid; i < 192 * 64; i += 128) {
        int m = i & 63, h = i >> 6;
        int r = r0 + m; if (r >= kROWS) r = kROWS - 1;
        Al[h * 64 + m] = xc[(size_t)r * kD + h];
    }
    __syncthreads();
    int rt = tid >> 4, ct = tid & 15;
    const float* bp = wpx + ct * 3;
    float acc[8][3];
    #pragma unroll
    for (int i = 0; i < 8; i++)
        #pragma unroll
        for (int j = 0; j < 3; j++) acc[i][j] = 0.f;
    for (int h = 0; h < 192; h++) {
        float4 a0 = *(const float4*)&Al[h * 64 + rt * 8];
        float4 a1 = *(const float4*)&Al[h * 64 + rt * 8 + 4];
        float b0 = bp[h * kDBLP], b1 = bp[h * kDBLP + 1], b2 = bp[h * kDBLP + 2];
        float ar[8] = {a0.x, a0.y, a0.z, a0.w, a1.x, a1.y, a1.z, a1.w};
        #pragma unroll
        for (int i = 0; i < 8; i++) {
            acc[i][0] += ar[i] * b0;
            acc[i][1] += ar[i] * b1;
            acc[i][2] += ar[i] * b2;
        }
    }
    int cbase = ct * 3;
    #pragma unroll
    for (int i = 0; i < 8; i++) {
        int r = r0 + rt * 8 + i;
        if (r >= kROWS) break;
        #pragma unroll
        for (int j = 0; j < 3; j++) {
            int c = cbase + j;
            if (c < kDBL) dbl[(size_t)r * kDBL + c] = acc[i][j];
        }
    }
}

// ---------------- mamba selective scan v2: n-parallel ----------------
// Grid (kBM, kD/16), block 256. Wave = 4 groups of 16 lanes; lane = (grp, n);
// each group owns one d, its 16 lanes own the 16 states. h-update is 1 FMA
// deep per t (exp arg independent of h); y = shfl-reduce over the 16 lanes.
// dt precomputed into LDS (no 16x-redundant softplus); B/C staged in LDS.
__global__ __launch_bounds__(256)
void scan_kernel(const float* __restrict__ dbl, const float* __restrict__ z,
                 float* __restrict__ xcy,
                 const float* __restrict__ A_log, const float* __restrict__ dtw,
                 const float* __restrict__ dtb, const float* __restrict__ Dp, int dir) {
    __shared__ float dt_lds[kT * 16];   // 6.4 KB
    __shared__ float bc_lds[kT * 32];   // 12.8 KB
    int bm = blockIdx.x;
    int d0 = blockIdx.y * 16;
    int tid = threadIdx.x;

    for (int i = tid; i < kT * 32; i += 256) {
        int t = i >> 5, j = i & 31;
        bc_lds[i] = dbl[((size_t)bm * kT + t) * kDBL + kR + j];
    }
    for (int i = tid; i < kT * 16; i += 256) {
        int t = i >> 4, dl = i & 15;
        int d = d0 + dl;
        const float* dr = dbl + ((size_t)bm * kT + t) * kDBL;
        float s = dtb[d];
        #pragma unroll
        for (int j = 0; j < kR; j++) s += dr[j] * dtw[d * kR + j];
        dt_lds[i] = softplus_f(s);
    }
    __syncthreads();

    int lane = tid & 63, wave = tid >> 6;
    int grp = lane >> 4, n = lane & 15;
    int dl = wave * 4 + grp;
    int d = d0 + dl;
    float A = -__expf(A_log[d * kN + n]);
    float Dv = Dp[d];
    float h = 0.f;
    for (int i = 0; i < kT; i++) {
        int t = dir ? (kT - 1 - i) : i;
        size_t rb = (size_t)bm * kT + t;
        float dt = dt_lds[t * 16 + dl];
        float Bv = bc_lds[t * 32 + n];
        float Cv = bc_lds[t * 32 + 16 + n];
        float xv = xcy[rb * kD + d];
        h = __expf(dt * A) * h + (dt * xv) * Bv;
        float p = h * Cv;
        p += __shfl_xor(p, 1, 16);
        p += __shfl_xor(p, 2, 16);
        p += __shfl_xor(p, 4, 16);
        p += __shfl_xor(p, 8, 16);
        if (n == 0) {
            float zv = z[rb * kD + d];
            xcy[rb * kD + d] = (p + xv * Dv) * silu_f(zv);
        }
    }
}

extern "C" void kernel_launch(void* const* d_in, const int* in_sizes, int n_in,
                              void* d_out, int out_size, void* d_ws, size_t ws_size,
                              hipStream_t stream) {
    const float* x       = (const float*)d_in[0];
    const float* ln1_g   = (const float*)d_in[1];
    const float* ln1_b   = (const float*)d_in[2];
    const float* conv1_w = (const float*)d_in[3];
    const float* conv1_b = (const float*)d_in[4];
    const float* prelu1  = (const float*)d_in[5];
    const float* lnf_g   = (const float*)d_in[6];
    const float* lnf_b   = (const float*)d_in[7];
    const float* sq_w    = (const float*)d_in[8];
    const float* sq_b    = (const float*)d_in[9];
    const float* full_w  = (const float*)d_in[10];
    const float* full_b  = (const float*)d_in[11];
    const float* unsq_w  = (const float*)d_in[12];
    const float* unsq_b  = (const float*)d_in[13];
    const float* ln2_g   = (const float*)d_in[14];
    const float* ln2_b   = (const float*)d_in[15];
    const float* conv2_w = (const float*)d_in[16];
    const float* conv2_b = (const float*)d_in[17];
    const float* prelu2  = (const float*)d_in[18];
    const float* lnm_g   = (const float*)d_in[19];
    const float* lnm_b   = (const float*)d_in[20];

    float* ws   = (float*)d_ws;
    float* xbuf = ws;
    float* xn   = ws + (size_t)kNX;
    float* bufA = ws + 2 * (size_t)kNX;          // kNM: ln-out / xin / dbl
    float* bufB = bufA + (size_t)kNM;            // kNM: s1 / z
    float* bufC = bufB + (size_t)kNM;            // kNM: s2 / xc / ymid
    float* wTs  = bufC + (size_t)kNM;
    float* in_wT[2]  = { wTs, wTs + 2 * kD * kH };                  // [96][384]
    float* out_wp[2] = { wTs + 2 * (2 * kD * kH),
                         wTs + 2 * (2 * kD * kH) + kD * 128 };      // [192][128]
    float* xp_wp[2]  = { wTs + 2 * (2 * kD * kH) + 2 * kD * 128,
                         wTs + 2 * (2 * kD * kH) + 2 * kD * 128 + kD * kDBLP }; // [192][48]

    for (int dir = 0; dir < 2; dir++) {
        int wi = 21 + dir * 9;
        const float* in_w  = (const float*)d_in[wi + 0];
        const float* xp_w  = (const float*)d_in[wi + 3];
        const float* out_w = (const float*)d_in[wi + 8];
        transpose_kernel<<<(2 * kD * kH + 255) / 256, 256, 0, stream>>>(in_w, in_wT[dir], 2 * kD, kH);
        outpad_kernel<<<(kD * 128 + 255) / 256, 256, 0, stream>>>(out_w, out_wp[dir]);
        xppad_kernel<<<(kD * kDBLP + 255) / 256, 256, 0, stream>>>(xp_w, xp_wp[dir]);
    }

    int lnGrid = (kROWS + 3) / 4;
    int nxGrid = (kNX + 255) / 256;
    dim3 fcGrid(kG, kT, kB);

    // stage 1: x = x + fconv(x)
    ln_kernel<<<lnGrid, 256, 0, stream>>>(x, bufA, ln1_g, ln1_b, kROWS);
    fconv_kernel<<<fcGrid, 256, 0, stream>>>(bufA, x, xbuf, conv1_w, conv1_b, prelu1);

    // stage 2: x = x + full(x)
    ln_kernel<<<lnGrid, 256, 0, stream>>>(xbuf, bufA, lnf_g, lnf_b, kROWS);
    squeeze_kernel<<<dim3(kB * kT, (kF + 63) / 64), 64, 0, stream>>>(bufA, bufB, sq_w, sq_b);
    fullmat_gemm<<<dim3(5, 4, kS), 256, 0, stream>>>(bufB, bufC, full_w, full_b);
    unsqueeze_kernel<<<nxGrid, 256, 0, stream>>>(bufC, xbuf, unsq_w, unsq_b);

    // stage 3: x = x + fconv(x)  (in-place: resid == out)
    ln_kernel<<<lnGrid, 256, 0, stream>>>(xbuf, bufA, ln2_g, ln2_b, kROWS);
    fconv_kernel<<<fcGrid, 256, 0, stream>>>(bufA, xbuf, xbuf, conv2_w, conv2_b, prelu2);

    // mamba input: xn = LN(x)
    ln_kernel<<<lnGrid, 256, 0, stream>>>(xbuf, xn, lnm_g, lnm_b, kROWS);

    for (int dir = 0; dir < 2; dir++) {
        int wi = 21 + dir * 9;
        const float* conv_w = (const float*)d_in[wi + 1];
        const float* conv_b = (const float*)d_in[wi + 2];
        const float* dt_w   = (const float*)d_in[wi + 4];
        const float* dt_b   = (const float*)d_in[wi + 5];
        const float* A_log  = (const float*)d_in[wi + 6];
        const float* Dp     = (const float*)d_in[wi + 7];

        inproj_gemm<<<dim3((kROWS + 63) / 64, 3), 128, 0, stream>>>(xn, in_wT[dir], bufA, bufB);
        mconv_kernel<<<(kROWS * 48 + 255) / 256, 256, 0, stream>>>(bufA, bufC, conv_w, conv_b, dir);
        xpproj_gemm<<<(kROWS + 63) / 64, 128, 0, stream>>>(bufC, bufA, xp_wp[dir]);
        scan_kernel<<<dim3(kBM, kD / 16), 256, 0, stream>>>(bufA, bufB, bufC, A_log, dt_w, dt_b, Dp, dir);
        outproj_gemm<<<(kROWS + 63) / 64, 128, 0, stream>>>(bufC, out_wp[dir], xbuf, (float*)d_out, dir);
    }
}

// Round 6
// 1265.668 us; speedup vs baseline: 1.1417x; 1.1417x over previous
//
#include <hip/hip_runtime.h>
#include <math.h>

// Problem constants
constexpr int kB   = 2;
constexpr int kF   = 257;   // FQ
constexpr int kT   = 100;
constexpr int kH   = 96;
constexpr int kS   = 8;
constexpr int kD   = 192;   // DIN
constexpr int kN   = 16;
constexpr int kR   = 6;
constexpr int kKF  = 5;
constexpr int kKM  = 4;
constexpr int kG   = 8;     // GROUPS
constexpr int kGC  = kH / kG;        // 12
constexpr int kBM  = kB * kF;        // 514
constexpr int kROWS = kB * kF * kT;  // 51400
constexpr int kNX  = kROWS * kH;     // 4,934,400
constexpr int kNM  = kROWS * kD;     // 9,868,800
constexpr int kDBL = kR + 2 * kN;    // 38
constexpr int kDBLP = 48;            // padded

__device__ inline float wave_reduce_sum(float v) {
    for (int o = 32; o > 0; o >>= 1) v += __shfl_xor(v, o, 64);
    return v;
}
__device__ inline float silu_f(float x) { return x / (1.f + __expf(-x)); }
__device__ inline float softplus_f(float x) { return x > 20.f ? x : log1pf(__expf(x)); }

// ---------------- LayerNorm over H=96, one wave per row ----------------
__global__ void ln_kernel(const float* __restrict__ in, float* __restrict__ out,
                          const float* __restrict__ g, const float* __restrict__ b,
                          int rows) {
    int wave = threadIdx.x >> 6;
    int lane = threadIdx.x & 63;
    int r = blockIdx.x * 4 + wave;
    if (r >= rows) return;
    const float* p = in + (size_t)r * kH;
    float v0 = p[lane];
    float v1 = (lane < 32) ? p[64 + lane] : 0.f;
    float s = wave_reduce_sum(v0 + v1);
    float mean = s * (1.f / 96.f);
    float d0 = v0 - mean;
    float d1 = (lane < 32) ? (v1 - mean) : 0.f;
    float vs = wave_reduce_sum(d0 * d0 + d1 * d1);
    float rstd = rsqrtf(vs * (1.f / 96.f) + 1e-5f);
    float* q = out + (size_t)r * kH;
    q[lane] = d0 * rstd * g[lane] + b[lane];
    if (lane < 32) q[64 + lane] = d1 * rstd * g[64 + lane] + b[64 + lane];
}

// ---------------- freq-conv stage ----------------
#define FDOT(S,K) \
  acc += xw[S][0].x*wr[K][0] + xw[S][0].y*wr[K][1] + xw[S][0].z*wr[K][2] + xw[S][0].w*wr[K][3] \
       + xw[S][1].x*wr[K][4] + xw[S][1].y*wr[K][5] + xw[S][1].z*wr[K][6] + xw[S][1].w*wr[K][7] \
       + xw[S][2].x*wr[K][8] + xw[S][2].y*wr[K][9] + xw[S][2].z*wr[K][10]+ xw[S][2].w*wr[K][11];

#define FSTEP(S0,S1,S2,S3,S4)                                              \
  if (f < fmax) {                                                          \
    const float4* cp = (const float4*)(Xs + (f + 4) * 12);                 \
    xw[S4][0] = cp[0]; xw[S4][1] = cp[1]; xw[S4][2] = cp[2];               \
    float acc = bias;                                                      \
    FDOT(S0,0) FDOT(S1,1) FDOT(S2,2) FDOT(S3,3) FDOT(S4,4)                 \
    float yv = acc > 0.f ? acc : alpha_h * acc;                            \
    size_t oi = ((size_t)(bb * kF + f) * kT + tt) * kH + g12 + hh;         \
    out[oi] = resid[oi] + yv;                                              \
    f++;                                                                   \
  }

__global__ __launch_bounds__(256)
void fconv_kernel(const float* __restrict__ ln, const float* __restrict__ resid,
                  float* __restrict__ out, const float* __restrict__ w,
                  const float* __restrict__ cb, const float* __restrict__ alpha) {
    __shared__ float Xs[261 * 12];
    __shared__ float Ws[kGC * kKF * 12];  // 720
    int g = blockIdx.x, tt = blockIdx.y, bb = blockIdx.z;
    int g12 = g * 12;
    int tid = threadIdx.x;

    for (int i = tid; i < 720; i += 256) Ws[i] = w[g * 720 + i];
    for (int i = tid; i < 257 * 12; i += 256) {
        int fs = i / 12, ci = i - fs * 12;
        Xs[(fs + 2) * 12 + ci] = ln[((size_t)(bb * kF + fs) * kT + tt) * kH + g12 + ci];
    }
    if (tid < 48) {
        const int padr[4] = {0, 1, 259, 260};
        Xs[padr[tid / 12] * 12 + (tid % 12)] = 0.f;
    }
    __syncthreads();

    int lane = tid & 63, wave = tid >> 6;
    int hh = lane % 12, fi = lane / 12;
    if (fi >= 5) return;                      // duplicate-slot lanes must retire (in-place race)
    int slot = wave * 5 + fi;
    int f0 = slot * 13;
    int fmax = min(f0 + 13, kF);

    float wr[5][12];
    #pragma unroll
    for (int k = 0; k < 5; k++)
        #pragma unroll
        for (int ci = 0; ci < 12; ci++)
            wr[k][ci] = Ws[hh * 60 + ci * 5 + k];

    float bias = cb[g12 + hh];
    float alpha_h = alpha[g12 + hh];

    float4 xw[5][3];
    #pragma unroll
    for (int s = 0; s < 4; s++) {
        int row = min(f0 + s, 260);
        const float4* cp = (const float4*)(Xs + row * 12);
        xw[s][0] = cp[0]; xw[s][1] = cp[1]; xw[s][2] = cp[2];
    }
    int f = f0;
    for (int rep = 0; rep < 3; rep++) {
        FSTEP(0,1,2,3,4)
        FSTEP(1,2,3,4,0)
        FSTEP(2,3,4,0,1)
        FSTEP(3,4,0,1,2)
        FSTEP(4,0,1,2,3)
    }
}

// ---------------- full stage: squeeze H->S with SiLU ----------------
__global__ void squeeze_kernel(const float* __restrict__ ln, float* __restrict__ s1,
                               const float* __restrict__ sqw, const float* __restrict__ sqb) {
    int bt = blockIdx.x;                       // b*kT + t
    int f = blockIdx.y * 64 + threadIdx.x;
    if (f >= kF) return;
    int b = bt / kT, t = bt % kT;
    const float* row = ln + ((size_t)(b * kF + f) * kT + t) * kH;
    float acc[kS];
    for (int s = 0; s < kS; s++) acc[s] = 0.f;
    for (int h = 0; h < kH; h++) {
        float v = row[h];
        for (int s = 0; s < kS; s++) acc[s] += v * sqw[s * kH + h];
    }
    for (int s = 0; s < kS; s++)
        s1[((size_t)bt * kS + s) * kF + f] = silu_f(acc[s] + sqb[s]);
}

// ---------------- full stage: per-group GEMM over F ----------------
__global__ __launch_bounds__(256)
void fullmat_gemm(const float* __restrict__ s1, float* __restrict__ s2,
                  const float* __restrict__ fw, const float* __restrict__ fb) {
    __shared__ float As[64 * 64];  // [fk][bt]
    __shared__ float Bs[64 * 64];  // [fk][k]
    int k0 = blockIdx.x * 64, bt0 = blockIdx.y * 64, g = blockIdx.z;
    int tid = threadIdx.x;
    int rt = tid >> 4, ct = tid & 15;
    float acc[4][4];
    #pragma unroll
    for (int i = 0; i < 4; i++)
        #pragma unroll
        for (int j = 0; j < 4; j++) acc[i][j] = 0.f;

    for (int f0 = 0; f0 < kF; f0 += 64) {
        int fcnt = min(64, kF - f0);
        for (int i = tid; i < 64 * 64; i += 256) {
            int m = i & 63, fk = i >> 6;
            int bt = bt0 + m, f = f0 + fk;
            As[fk * 64 + m] = (bt < kB * kT && f < kF)
                ? s1[((size_t)bt * kS + g) * kF + f] : 0.f;
            int k = k0 + m;
            Bs[fk * 64 + m] = (k < kF && f < kF)
                ? fw[(size_t)g * kF * kF + (size_t)k * kF + f] : 0.f;
        }
        __syncthreads();
        for (int f = 0; f < fcnt; f++) {
            float4 a4 = *(const float4*)&As[f * 64 + rt * 4];
            float4 b4 = *(const float4*)&Bs[f * 64 + ct * 4];
            float ar[4] = {a4.x, a4.y, a4.z, a4.w};
            float br[4] = {b4.x, b4.y, b4.z, b4.w};
            #pragma unroll
            for (int i = 0; i < 4; i++)
                #pragma unroll
                for (int j = 0; j < 4; j++) acc[i][j] += ar[i] * br[j];
        }
        __syncthreads();
    }
    #pragma unroll
    for (int i = 0; i < 4; i++) {
        int bt = bt0 + rt * 4 + i;
        if (bt >= kB * kT) continue;
        #pragma unroll
        for (int j = 0; j < 4; j++) {
            int k = k0 + ct * 4 + j;
            if (k >= kF) continue;
            s2[((size_t)bt * kS + g) * kF + k] = acc[i][j] + fb[g * kF + k];
        }
    }
}

// ---------------- full stage: unsqueeze S->H + SiLU + residual ----------------
__global__ void unsqueeze_kernel(const float* __restrict__ s2, float* __restrict__ x,
                                 const float* __restrict__ uw, const float* __restrict__ ub) {
    int idx = blockIdx.x * blockDim.x + threadIdx.x;
    if (idx >= kNX) return;
    int h = idx % kH;
    int t = (idx / kH) % kT;
    int f = (idx / (kH * kT)) % kF;
    int b = idx / (kH * kT * kF);
    int bt = b * kT + t;
    float acc = ub[h];
    for (int s = 0; s < kS; s++)
        acc += s2[((size_t)bt * kS + s) * kF + f] * uw[h * kS + s];
    x[idx] += silu_f(acc);
}

// ---------------- small weight transpose ----------------
__global__ void transpose_kernel(const float* __restrict__ in, float* __restrict__ out,
                                 int rows, int cols) {
    int idx = blockIdx.x * blockDim.x + threadIdx.x;
    if (idx >= rows * cols) return;
    int r = idx / cols, c = idx % cols;
    out[c * rows + r] = in[idx];
}

// out_w [96][192] -> padded transpose wp [192][128] (cols >=96 zero)
__global__ void outpad_kernel(const float* __restrict__ w, float* __restrict__ wp) {
    int i = blockIdx.x * 256 + threadIdx.x;
    if (i >= kD * 128) return;
    int d = i >> 7, h = i & 127;
    wp[i] = (h < kH) ? w[h * kD + d] : 0.f;
}

// xp_w [38][192] -> padded transpose wpx [192][48] (cols >=38 zero)
__global__ void xppad_kernel(const float* __restrict__ w, float* __restrict__ wp) {
    int i = blockIdx.x * 256 + threadIdx.x;
    if (i >= kD * kDBLP) return;
    int d = i / kDBLP, n = i % kDBLP;
    wp[i] = (n < kDBL) ? w[n * kD + d] : 0.f;
}

// ---------------- mamba in-proj GEMM: [51400x96] @ [96x384] ----------------
__global__ __launch_bounds__(128)
void inproj_gemm(const float* __restrict__ xn, const float* __restrict__ wT,
                 float* __restrict__ xin, float* __restrict__ z) {
    __shared__ float Al[96 * 64];
    int r0 = blockIdx.x * 64;
    int c0 = blockIdx.y * 128;
    int tid = threadIdx.x;
    for (int i = tid; i < 96 * 64; i += 128) {
        int m = i & 63, h = i >> 6;
        int r = r0 + m; if (r >= kROWS) r = kROWS - 1;
        Al[h * 64 + m] = xn[(size_t)r * kH + h];
    }
    __syncthreads();
    int rt = tid >> 4, ct = tid & 15;
    const float* bp = wT + c0 + ct * 8;
    float4 acc[8][2];
    #pragma unroll
    for (int i = 0; i < 8; i++) {
        acc[i][0] = make_float4(0.f, 0.f, 0.f, 0.f);
        acc[i][1] = make_float4(0.f, 0.f, 0.f, 0.f);
    }
    for (int h = 0; h < 96; h++) {
        float4 a0 = *(const float4*)&Al[h * 64 + rt * 8];
        float4 a1 = *(const float4*)&Al[h * 64 + rt * 8 + 4];
        float4 b0 = *(const float4*)&bp[(size_t)h * 384];
        float4 b1 = *(const float4*)&bp[(size_t)h * 384 + 4];
        float ar[8] = {a0.x, a0.y, a0.z, a0.w, a1.x, a1.y, a1.z, a1.w};
        #pragma unroll
        for (int i = 0; i < 8; i++) {
            float av = ar[i];
            acc[i][0].x += av * b0.x; acc[i][0].y += av * b0.y;
            acc[i][0].z += av * b0.z; acc[i][0].w += av * b0.w;
            acc[i][1].x += av * b1.x; acc[i][1].y += av * b1.y;
            acc[i][1].z += av * b1.z; acc[i][1].w += av * b1.w;
        }
    }
    int cbase = c0 + ct * 8;
    #pragma unroll
    for (int i = 0; i < 8; i++) {
        int r = r0 + rt * 8 + i;
        if (r >= kROWS) break;
        if (cbase < kD) {
            *(float4*)&xin[(size_t)r * kD + cbase]     = acc[i][0];
            *(float4*)&xin[(size_t)r * kD + cbase + 4] = acc[i][1];
        } else {
            *(float4*)&z[(size_t)r * kD + cbase - kD]     = acc[i][0];
            *(float4*)&z[(size_t)r * kD + cbase - kD + 4] = acc[i][1];
        }
    }
}

// ---------------- mamba out-proj GEMM + combine: [51400x192] @ [192x128pad] ----------------
__global__ __launch_bounds__(128)
void outproj_gemm(const float* __restrict__ ym, const float* __restrict__ wp,
                  const float* __restrict__ xres, float* __restrict__ out, int dir) {
    __shared__ float Al[192 * 64];  // 48 KiB
    int r0 = blockIdx.x * 64;
    int tid = threadIdx.x;
    for (int i = tid; i < 192 * 64; i += 128) {
        int m = i & 63, h = i >> 6;
        int r = r0 + m; if (r >= kROWS) r = kROWS - 1;
        Al[h * 64 + m] = ym[(size_t)r * kD + h];
    }
    __syncthreads();
    int rt = tid >> 4, ct = tid & 15;
    const float* bp = wp + ct * 8;
    float4 acc[8][2];
    #pragma unroll
    for (int i = 0; i < 8; i++) {
        acc[i][0] = make_float4(0.f, 0.f, 0.f, 0.f);
        acc[i][1] = make_float4(0.f, 0.f, 0.f, 0.f);
    }
    for (int h = 0; h < 192; h++) {
        float4 a0 = *(const float4*)&Al[h * 64 + rt * 8];
        float4 a1 = *(const float4*)&Al[h * 64 + rt * 8 + 4];
        float4 b0 = *(const float4*)&bp[h * 128];
        float4 b1 = *(const float4*)&bp[h * 128 + 4];
        float ar[8] = {a0.x, a0.y, a0.z, a0.w, a1.x, a1.y, a1.z, a1.w};
        #pragma unroll
        for (int i = 0; i < 8; i++) {
            float av = ar[i];
            acc[i][0].x += av * b0.x; acc[i][0].y += av * b0.y;
            acc[i][0].z += av * b0.z; acc[i][0].w += av * b0.w;
            acc[i][1].x += av * b1.x; acc[i][1].y += av * b1.y;
            acc[i][1].z += av * b1.z; acc[i][1].w += av * b1.w;
        }
    }
    int cbase = ct * 8;
    if (cbase >= kH) return;
    #pragma unroll
    for (int i = 0; i < 8; i++) {
        int r = r0 + rt * 8 + i;
        if (r >= kROWS) break;
        float4 v0 = acc[i][0], v1 = acc[i][1];
        size_t o = (size_t)r * kH + cbase;
        if (dir == 0) {
            float4 x0 = *(const float4*)&xres[o], x1 = *(const float4*)&xres[o + 4];
            v0.x = x0.x + 0.5f * v0.x; v0.y = x0.y + 0.5f * v0.y;
            v0.z = x0.z + 0.5f * v0.z; v0.w = x0.w + 0.5f * v0.w;
            v1.x = x1.x + 0.5f * v1.x; v1.y = x1.y + 0.5f * v1.y;
            v1.z = x1.z + 0.5f * v1.z; v1.w = x1.w + 0.5f * v1.w;
        } else {
            float4 x0 = *(const float4*)&out[o], x1 = *(const float4*)&out[o + 4];
            v0.x = x0.x + 0.5f * v0.x; v0.y = x0.y + 0.5f * v0.y;
            v0.z = x0.z + 0.5f * v0.z; v0.w = x0.w + 0.5f * v0.w;
            v1.x = x1.x + 0.5f * v1.x; v1.y = x1.y + 0.5f * v1.y;
            v1.z = x1.z + 0.5f * v1.z; v1.w = x1.w + 0.5f * v1.w;
        }
        *(float4*)&out[o] = v0;
        *(float4*)&out[o + 4] = v1;
    }
}

// ---------------- mamba depthwise conv over T + SiLU ----------------
__global__ void mconv_kernel(const float* __restrict__ xin, float* __restrict__ xc,
                             const float* __restrict__ cw, const float* __restrict__ cb, int dir) {
    int qid = blockIdx.x * blockDim.x + threadIdx.x;
    if (qid >= kROWS * 48) return;
    int r = qid / 48, d4 = (qid - r * 48) * 4;
    int bm = r / kT, t = r - bm * kT;
    float4 acc = make_float4(cb[d4], cb[d4 + 1], cb[d4 + 2], cb[d4 + 3]);
    #pragma unroll
    for (int k = 0; k < kKM; k++) {
        int ts = dir ? (t + 3 - k) : (t + k - 3);
        if (ts < 0 || ts >= kT) continue;
        float4 v = *(const float4*)&xin[((size_t)bm * kT + ts) * kD + d4];
        acc.x += v.x * cw[(d4 + 0) * kKM + k];
        acc.y += v.y * cw[(d4 + 1) * kKM + k];
        acc.z += v.z * cw[(d4 + 2) * kKM + k];
        acc.w += v.w * cw[(d4 + 3) * kKM + k];
    }
    float4 o = make_float4(silu_f(acc.x), silu_f(acc.y), silu_f(acc.z), silu_f(acc.w));
    *(float4*)&xc[(size_t)r * kD + d4] = o;
}

// ---------------- mamba x-proj GEMM: [51400x192] @ [192x48pad] ----------------
__global__ __launch_bounds__(128)
void xpproj_gemm(const float* __restrict__ xc, float* __restrict__ dbl,
                 const float* __restrict__ wpx) {
    __shared__ float Al[192 * 64];  // 48 KiB
    int r0 = blockIdx.x * 64;
    int tid = threadIdx.x;
    for (int i = tid; i < 192 * 64; i += 128) {
        int m = i & 63, h = i >> 6;
        int r = r0 + m; if (r >= kROWS) r = kROWS - 1;
        Al[h * 64 + m] = xc[(size_t)r * kD + h];
    }
    __syncthreads();
    int rt = tid >> 4, ct = tid & 15;
    const float* bp = wpx + ct * 3;
    float acc[8][3];
    #pragma unroll
    for (int i = 0; i < 8; i++)
        #pragma unroll
        for (int j = 0; j < 3; j++) acc[i][j] = 0.f;
    for (int h = 0; h < 192; h++) {
        float4 a0 = *(const float4*)&Al[h * 64 + rt * 8];
        float4 a1 = *(const float4*)&Al[h * 64 + rt * 8 + 4];
        float b0 = bp[h * kDBLP], b1 = bp[h * kDBLP + 1], b2 = bp[h * kDBLP + 2];
        float ar[8] = {a0.x, a0.y, a0.z, a0.w, a1.x, a1.y, a1.z, a1.w};
        #pragma unroll
        for (int i = 0; i < 8; i++) {
            acc[i][0] += ar[i] * b0;
            acc[i][1] += ar[i] * b1;
            acc[i][2] += ar[i] * b2;
        }
    }
    int cbase = ct * 3;
    #pragma unroll
    for (int i = 0; i < 8; i++) {
        int r = r0 + rt * 8 + i;
        if (r >= kROWS) break;
        #pragma unroll
        for (int j = 0; j < 3; j++) {
            int c = cbase + j;
            if (c < kDBL) dbl[(size_t)r * kDBL + c] = acc[i][j];
        }
    }
}

// ---------------- mamba selective scan v3: T-chunked two-phase ----------------
// One block per bm, 768 threads = (chunk c in 0..3) x (d in 0..191); 12 waves.
// Linear recurrence => chunk c's incoming state h_in satisfies
//   h_in(c+1) = exp(A*sdt_c) (.) h_in(c) + h_local(c),
// where sdt_c = sum of dt over the chunk (decay product collapses to one
// scalar per thread). Phase 1: local scan from 0 (track sdt). Phase 2:
// 4-step LDS propagation (reverse order for dir=1). Phase 3: rescan from
// the corrected initial state and emit outputs. Thread-per-(bm,d) keeps all
// lane work non-redundant; 4x the waves of the monolithic scan, half the
// serial depth.
__global__ __launch_bounds__(768)
void scan_kernel(const float* __restrict__ dbl, const float* __restrict__ z,
                 float* __restrict__ xcy,
                 const float* __restrict__ A_log, const float* __restrict__ dtw,
                 const float* __restrict__ dtb, const float* __restrict__ Dp, int dir) {
    __shared__ float hin_lds[kD * kN];  // 12.3 KB
    constexpr int CL = kT / 4;          // 25
    int bm = blockIdx.x;
    int tid = threadIdx.x;
    int c = tid / kD;                   // chunk id; 192 = 3 waves -> wave-uniform
    int d = tid - c * kD;
    int lo = c * CL, hi = lo + CL - 1;

    float A[kN];
    #pragma unroll
    for (int n = 0; n < kN; n++) A[n] = -__expf(A_log[d * kN + n]);
    float dw[kR];
    #pragma unroll
    for (int j = 0; j < kR; j++) dw[j] = dtw[d * kR + j];
    float db = dtb[d], Dv = Dp[d];

    // phase 1: local chunk scan with h_in = 0; accumulate sdt
    float h[kN];
    #pragma unroll
    for (int n = 0; n < kN; n++) h[n] = 0.f;
    float sdt = 0.f;
    for (int i = 0; i < CL; i++) {
        int t = dir ? (hi - i) : (lo + i);
        size_t rb = (size_t)bm * kT + t;
        const float* dr = dbl + rb * kDBL;
        float s = db;
        #pragma unroll
        for (int j = 0; j < kR; j++) s += dr[j] * dw[j];
        float dt = softplus_f(s);
        sdt += dt;
        float dtx = dt * xcy[rb * kD + d];
        #pragma unroll
        for (int n = 0; n < kN; n++)
            h[n] = __expf(dt * A[n]) * h[n] + dtx * dr[kR + n];
    }

    // phase 2: sequential cross-chunk propagation through LDS.
    // After this, h[] = this chunk's true incoming state.
    for (int s = 0; s < 4; s++) {
        int cc = dir ? (3 - s) : s;
        if (c == cc) {
            #pragma unroll
            for (int n = 0; n < kN; n++) {
                float hin = (s == 0) ? 0.f : hin_lds[d * kN + n];
                hin_lds[d * kN + n] = __expf(A[n] * sdt) * hin + h[n];
                h[n] = hin;
            }
        }
        __syncthreads();
    }

    // phase 3: rescan with correct initial state, emit outputs
    for (int i = 0; i < CL; i++) {
        int t = dir ? (hi - i) : (lo + i);
        size_t rb = (size_t)bm * kT + t;
        const float* dr = dbl + rb * kDBL;
        float s = db;
        #pragma unroll
        for (int j = 0; j < kR; j++) s += dr[j] * dw[j];
        float dt = softplus_f(s);
        float xv = xcy[rb * kD + d];
        float dtx = dt * xv;
        float y = 0.f;
        #pragma unroll
        for (int n = 0; n < kN; n++) {
            h[n] = __expf(dt * A[n]) * h[n] + dtx * dr[kR + n];
            y += h[n] * dr[kR + kN + n];
        }
        float zv = z[rb * kD + d];
        xcy[rb * kD + d] = (y + xv * Dv) * silu_f(zv);
    }
}

extern "C" void kernel_launch(void* const* d_in, const int* in_sizes, int n_in,
                              void* d_out, int out_size, void* d_ws, size_t ws_size,
                              hipStream_t stream) {
    const float* x       = (const float*)d_in[0];
    const float* ln1_g   = (const float*)d_in[1];
    const float* ln1_b   = (const float*)d_in[2];
    const float* conv1_w = (const float*)d_in[3];
    const float* conv1_b = (const float*)d_in[4];
    const float* prelu1  = (const float*)d_in[5];
    const float* lnf_g   = (const float*)d_in[6];
    const float* lnf_b   = (const float*)d_in[7];
    const float* sq_w    = (const float*)d_in[8];
    const float* sq_b    = (const float*)d_in[9];
    const float* full_w  = (const float*)d_in[10];
    const float* full_b  = (const float*)d_in[11];
    const float* unsq_w  = (const float*)d_in[12];
    const float* unsq_b  = (const float*)d_in[13];
    const float* ln2_g   = (const float*)d_in[14];
    const float* ln2_b   = (const float*)d_in[15];
    const float* conv2_w = (const float*)d_in[16];
    const float* conv2_b = (const float*)d_in[17];
    const float* prelu2  = (const float*)d_in[18];
    const float* lnm_g   = (const float*)d_in[19];
    const float* lnm_b   = (const float*)d_in[20];

    float* ws   = (float*)d_ws;
    float* xbuf = ws;
    float* xn   = ws + (size_t)kNX;
    float* bufA = ws + 2 * (size_t)kNX;          // kNM: ln-out / xin / dbl
    float* bufB = bufA + (size_t)kNM;            // kNM: s1 / z
    float* bufC = bufB + (size_t)kNM;            // kNM: s2 / xc / ymid
    float* wTs  = bufC + (size_t)kNM;
    float* in_wT[2]  = { wTs, wTs + 2 * kD * kH };                  // [96][384]
    float* out_wp[2] = { wTs + 2 * (2 * kD * kH),
                         wTs + 2 * (2 * kD * kH) + kD * 128 };      // [192][128]
    float* xp_wp[2]  = { wTs + 2 * (2 * kD * kH) + 2 * kD * 128,
                         wTs + 2 * (2 * kD * kH) + 2 * kD * 128 + kD * kDBLP }; // [192][48]

    for (int dir = 0; dir < 2; dir++) {
        int wi = 21 + dir * 9;
        const float* in_w  = (const float*)d_in[wi + 0];
        const float* xp_w  = (const float*)d_in[wi + 3];
        const float* out_w = (const float*)d_in[wi + 8];
        transpose_kernel<<<(2 * kD * kH + 255) / 256, 256, 0, stream>>>(in_w, in_wT[dir], 2 * kD, kH);
        outpad_kernel<<<(kD * 128 + 255) / 256, 256, 0, stream>>>(out_w, out_wp[dir]);
        xppad_kernel<<<(kD * kDBLP + 255) / 256, 256, 0, stream>>>(xp_w, xp_wp[dir]);
    }

    int lnGrid = (kROWS + 3) / 4;
    int nxGrid = (kNX + 255) / 256;
    dim3 fcGrid(kG, kT, kB);

    // stage 1: x = x + fconv(x)
    ln_kernel<<<lnGrid, 256, 0, stream>>>(x, bufA, ln1_g, ln1_b, kROWS);
    fconv_kernel<<<fcGrid, 256, 0, stream>>>(bufA, x, xbuf, conv1_w, conv1_b, prelu1);

    // stage 2: x = x + full(x)
    ln_kernel<<<lnGrid, 256, 0, stream>>>(xbuf, bufA, lnf_g, lnf_b, kROWS);
    squeeze_kernel<<<dim3(kB * kT, (kF + 63) / 64), 64, 0, stream>>>(bufA, bufB, sq_w, sq_b);
    fullmat_gemm<<<dim3(5, 4, kS), 256, 0, stream>>>(bufB, bufC, full_w, full_b);
    unsqueeze_kernel<<<nxGrid, 256, 0, stream>>>(bufC, xbuf, unsq_w, unsq_b);

    // stage 3: x = x + fconv(x)  (in-place: resid == out)
    ln_kernel<<<lnGrid, 256, 0, stream>>>(xbuf, bufA, ln2_g, ln2_b, kROWS);
    fconv_kernel<<<fcGrid, 256, 0, stream>>>(bufA, xbuf, xbuf, conv2_w, conv2_b, prelu2);

    // mamba input: xn = LN(x)
    ln_kernel<<<lnGrid, 256, 0, stream>>>(xbuf, xn, lnm_g, lnm_b, kROWS);

    for (int dir = 0; dir < 2; dir++) {
        int wi = 21 + dir * 9;
        const float* conv_w = (const float*)d_in[wi + 1];
        const float* conv_b = (const float*)d_in[wi + 2];
        const float* dt_w   = (const float*)d_in[wi + 4];
        const float* dt_b   = (const float*)d_in[wi + 5];
        const float* A_log  = (const float*)d_in[wi + 6];
        const float* Dp     = (const float*)d_in[wi + 7];

        inproj_gemm<<<dim3((kROWS + 63) / 64, 3), 128, 0, stream>>>(xn, in_wT[dir], bufA, bufB);
        mconv_kernel<<<(kROWS * 48 + 255) / 256, 256, 0, stream>>>(bufA, bufC, conv_w, conv_b, dir);
        xpproj_gemm<<<(kROWS + 63) / 64, 128, 0, stream>>>(bufC, bufA, xp_wp[dir]);
        scan_kernel<<<kBM, 768, 0, stream>>>(bufA, bufB, bufC, A_log, dt_w, dt_b, Dp, dir);
        outproj_gemm<<<(kROWS + 63) / 64, 128, 0, stream>>>(bufC, out_wp[dir], xbuf, (float*)d_out, dir);
    }
}

// Round 7
// 1195.592 us; speedup vs baseline: 1.2087x; 1.0586x over previous
//
#include <hip/hip_runtime.h>
#include <math.h>

// Problem constants
constexpr int kB   = 2;
constexpr int kF   = 257;   // FQ
constexpr int kT   = 100;
constexpr int kH   = 96;
constexpr int kS   = 8;
constexpr int kD   = 192;   // DIN
constexpr int kN   = 16;
constexpr int kR   = 6;
constexpr int kKF  = 5;
constexpr int kKM  = 4;
constexpr int kG   = 8;     // GROUPS
constexpr int kGC  = kH / kG;        // 12
constexpr int kBM  = kB * kF;        // 514
constexpr int kROWS = kB * kF * kT;  // 51400
constexpr int kNX  = kROWS * kH;     // 4,934,400
constexpr int kNM  = kROWS * kD;     // 9,868,800
constexpr int kDBL = kR + 2 * kN;    // 38
constexpr int kDBLP = 48;            // padded

__device__ inline float wave_reduce_sum(float v) {
    for (int o = 32; o > 0; o >>= 1) v += __shfl_xor(v, o, 64);
    return v;
}
__device__ inline float silu_f(float x) { return x / (1.f + __expf(-x)); }
__device__ inline float softplus_f(float x) { return x > 20.f ? x : log1pf(__expf(x)); }

// ---------------- LayerNorm over H=96, one wave per row ----------------
__global__ void ln_kernel(const float* __restrict__ in, float* __restrict__ out,
                          const float* __restrict__ g, const float* __restrict__ b,
                          int rows) {
    int wave = threadIdx.x >> 6;
    int lane = threadIdx.x & 63;
    int r = blockIdx.x * 4 + wave;
    if (r >= rows) return;
    const float* p = in + (size_t)r * kH;
    float v0 = p[lane];
    float v1 = (lane < 32) ? p[64 + lane] : 0.f;
    float s = wave_reduce_sum(v0 + v1);
    float mean = s * (1.f / 96.f);
    float d0 = v0 - mean;
    float d1 = (lane < 32) ? (v1 - mean) : 0.f;
    float vs = wave_reduce_sum(d0 * d0 + d1 * d1);
    float rstd = rsqrtf(vs * (1.f / 96.f) + 1e-5f);
    float* q = out + (size_t)r * kH;
    q[lane] = d0 * rstd * g[lane] + b[lane];
    if (lane < 32) q[64 + lane] = d1 * rstd * g[64 + lane] + b[64 + lane];
}

// ---------------- freq-conv stage ----------------
#define FDOT(S,K) \
  acc += xw[S][0].x*wr[K][0] + xw[S][0].y*wr[K][1] + xw[S][0].z*wr[K][2] + xw[S][0].w*wr[K][3] \
       + xw[S][1].x*wr[K][4] + xw[S][1].y*wr[K][5] + xw[S][1].z*wr[K][6] + xw[S][1].w*wr[K][7] \
       + xw[S][2].x*wr[K][8] + xw[S][2].y*wr[K][9] + xw[S][2].z*wr[K][10]+ xw[S][2].w*wr[K][11];

#define FSTEP(S0,S1,S2,S3,S4)                                              \
  if (f < fmax) {                                                          \
    const float4* cp = (const float4*)(Xs + (f + 4) * 12);                 \
    xw[S4][0] = cp[0]; xw[S4][1] = cp[1]; xw[S4][2] = cp[2];               \
    float acc = bias;                                                      \
    FDOT(S0,0) FDOT(S1,1) FDOT(S2,2) FDOT(S3,3) FDOT(S4,4)                 \
    float yv = acc > 0.f ? acc : alpha_h * acc;                            \
    size_t oi = ((size_t)(bb * kF + f) * kT + tt) * kH + g12 + hh;         \
    out[oi] = resid[oi] + yv;                                              \
    f++;                                                                   \
  }

__global__ __launch_bounds__(256)
void fconv_kernel(const float* __restrict__ ln, const float* __restrict__ resid,
                  float* __restrict__ out, const float* __restrict__ w,
                  const float* __restrict__ cb, const float* __restrict__ alpha) {
    __shared__ float Xs[261 * 12];
    __shared__ float Ws[kGC * kKF * 12];  // 720
    int g = blockIdx.x, tt = blockIdx.y, bb = blockIdx.z;
    int g12 = g * 12;
    int tid = threadIdx.x;

    for (int i = tid; i < 720; i += 256) Ws[i] = w[g * 720 + i];
    for (int i = tid; i < 257 * 12; i += 256) {
        int fs = i / 12, ci = i - fs * 12;
        Xs[(fs + 2) * 12 + ci] = ln[((size_t)(bb * kF + fs) * kT + tt) * kH + g12 + ci];
    }
    if (tid < 48) {
        const int padr[4] = {0, 1, 259, 260};
        Xs[padr[tid / 12] * 12 + (tid % 12)] = 0.f;
    }
    __syncthreads();

    int lane = tid & 63, wave = tid >> 6;
    int hh = lane % 12, fi = lane / 12;
    if (fi >= 5) return;                      // duplicate-slot lanes must retire (in-place race)
    int slot = wave * 5 + fi;
    int f0 = slot * 13;
    int fmax = min(f0 + 13, kF);

    float wr[5][12];
    #pragma unroll
    for (int k = 0; k < 5; k++)
        #pragma unroll
        for (int ci = 0; ci < 12; ci++)
            wr[k][ci] = Ws[hh * 60 + ci * 5 + k];

    float bias = cb[g12 + hh];
    float alpha_h = alpha[g12 + hh];

    float4 xw[5][3];
    #pragma unroll
    for (int s = 0; s < 4; s++) {
        int row = min(f0 + s, 260);
        const float4* cp = (const float4*)(Xs + row * 12);
        xw[s][0] = cp[0]; xw[s][1] = cp[1]; xw[s][2] = cp[2];
    }
    int f = f0;
    for (int rep = 0; rep < 3; rep++) {
        FSTEP(0,1,2,3,4)
        FSTEP(1,2,3,4,0)
        FSTEP(2,3,4,0,1)
        FSTEP(3,4,0,1,2)
        FSTEP(4,0,1,2,3)
    }
}

// ---------------- full stage: squeeze H->S with SiLU ----------------
__global__ void squeeze_kernel(const float* __restrict__ ln, float* __restrict__ s1,
                               const float* __restrict__ sqw, const float* __restrict__ sqb) {
    int bt = blockIdx.x;                       // b*kT + t
    int f = blockIdx.y * 64 + threadIdx.x;
    if (f >= kF) return;
    int b = bt / kT, t = bt % kT;
    const float* row = ln + ((size_t)(b * kF + f) * kT + t) * kH;
    float acc[kS];
    for (int s = 0; s < kS; s++) acc[s] = 0.f;
    for (int h = 0; h < kH; h++) {
        float v = row[h];
        for (int s = 0; s < kS; s++) acc[s] += v * sqw[s * kH + h];
    }
    for (int s = 0; s < kS; s++)
        s1[((size_t)bt * kS + s) * kF + f] = silu_f(acc[s] + sqb[s]);
}

// ---------------- full stage: per-group GEMM over F ----------------
__global__ __launch_bounds__(256)
void fullmat_gemm(const float* __restrict__ s1, float* __restrict__ s2,
                  const float* __restrict__ fw, const float* __restrict__ fb) {
    __shared__ float As[64 * 64];  // [fk][bt]
    __shared__ float Bs[64 * 64];  // [fk][k]
    int k0 = blockIdx.x * 64, bt0 = blockIdx.y * 64, g = blockIdx.z;
    int tid = threadIdx.x;
    int rt = tid >> 4, ct = tid & 15;
    float acc[4][4];
    #pragma unroll
    for (int i = 0; i < 4; i++)
        #pragma unroll
        for (int j = 0; j < 4; j++) acc[i][j] = 0.f;

    for (int f0 = 0; f0 < kF; f0 += 64) {
        int fcnt = min(64, kF - f0);
        for (int i = tid; i < 64 * 64; i += 256) {
            int m = i & 63, fk = i >> 6;
            int bt = bt0 + m, f = f0 + fk;
            As[fk * 64 + m] = (bt < kB * kT && f < kF)
                ? s1[((size_t)bt * kS + g) * kF + f] : 0.f;
            int k = k0 + m;
            Bs[fk * 64 + m] = (k < kF && f < kF)
                ? fw[(size_t)g * kF * kF + (size_t)k * kF + f] : 0.f;
        }
        __syncthreads();
        for (int f = 0; f < fcnt; f++) {
            float4 a4 = *(const float4*)&As[f * 64 + rt * 4];
            float4 b4 = *(const float4*)&Bs[f * 64 + ct * 4];
            float ar[4] = {a4.x, a4.y, a4.z, a4.w};
            float br[4] = {b4.x, b4.y, b4.z, b4.w};
            #pragma unroll
            for (int i = 0; i < 4; i++)
                #pragma unroll
                for (int j = 0; j < 4; j++) acc[i][j] += ar[i] * br[j];
        }
        __syncthreads();
    }
    #pragma unroll
    for (int i = 0; i < 4; i++) {
        int bt = bt0 + rt * 4 + i;
        if (bt >= kB * kT) continue;
        #pragma unroll
        for (int j = 0; j < 4; j++) {
            int k = k0 + ct * 4 + j;
            if (k >= kF) continue;
            s2[((size_t)bt * kS + g) * kF + k] = acc[i][j] + fb[g * kF + k];
        }
    }
}

// ---------------- full stage: unsqueeze S->H + SiLU + residual ----------------
__global__ void unsqueeze_kernel(const float* __restrict__ s2, float* __restrict__ x,
                                 const float* __restrict__ uw, const float* __restrict__ ub) {
    int idx = blockIdx.x * blockDim.x + threadIdx.x;
    if (idx >= kNX) return;
    int h = idx % kH;
    int t = (idx / kH) % kT;
    int f = (idx / (kH * kT)) % kF;
    int b = idx / (kH * kT * kF);
    int bt = b * kT + t;
    float acc = ub[h];
    for (int s = 0; s < kS; s++)
        acc += s2[((size_t)bt * kS + s) * kF + f] * uw[h * kS + s];
    x[idx] += silu_f(acc);
}

// ---------------- small weight transpose ----------------
__global__ void transpose_kernel(const float* __restrict__ in, float* __restrict__ out,
                                 int rows, int cols) {
    int idx = blockIdx.x * blockDim.x + threadIdx.x;
    if (idx >= rows * cols) return;
    int r = idx / cols, c = idx % cols;
    out[c * rows + r] = in[idx];
}

// out_w [96][192] -> padded transpose wp [192][128] (cols >=96 zero)
__global__ void outpad_kernel(const float* __restrict__ w, float* __restrict__ wp) {
    int i = blockIdx.x * 256 + threadIdx.x;
    if (i >= kD * 128) return;
    int d = i >> 7, h = i & 127;
    wp[i] = (h < kH) ? w[h * kD + d] : 0.f;
}

// xp_w [38][192] -> padded transpose wpx [192][48] (cols >=38 zero)
__global__ void xppad_kernel(const float* __restrict__ w, float* __restrict__ wp) {
    int i = blockIdx.x * 256 + threadIdx.x;
    if (i >= kD * kDBLP) return;
    int d = i / kDBLP, n = i % kDBLP;
    wp[i] = (n < kDBL) ? w[n * kD + d] : 0.f;
}

// ---------------- mamba in-proj GEMM: [51400x96] @ [96x384] ----------------
__global__ __launch_bounds__(128)
void inproj_gemm(const float* __restrict__ xn, const float* __restrict__ wT,
                 float* __restrict__ xin, float* __restrict__ z) {
    __shared__ float Al[96 * 64];
    int r0 = blockIdx.x * 64;
    int c0 = blockIdx.y * 128;
    int tid = threadIdx.x;
    for (int i = tid; i < 96 * 64; i += 128) {
        int m = i & 63, h = i >> 6;
        int r = r0 + m; if (r >= kROWS) r = kROWS - 1;
        Al[h * 64 + m] = xn[(size_t)r * kH + h];
    }
    __syncthreads();
    int rt = tid >> 4, ct = tid & 15;
    const float* bp = wT + c0 + ct * 8;
    float4 acc[8][2];
    #pragma unroll
    for (int i = 0; i < 8; i++) {
        acc[i][0] = make_float4(0.f, 0.f, 0.f, 0.f);
        acc[i][1] = make_float4(0.f, 0.f, 0.f, 0.f);
    }
    for (int h = 0; h < 96; h++) {
        float4 a0 = *(const float4*)&Al[h * 64 + rt * 8];
        float4 a1 = *(const float4*)&Al[h * 64 + rt * 8 + 4];
        float4 b0 = *(const float4*)&bp[(size_t)h * 384];
        float4 b1 = *(const float4*)&bp[(size_t)h * 384 + 4];
        float ar[8] = {a0.x, a0.y, a0.z, a0.w, a1.x, a1.y, a1.z, a1.w};
        #pragma unroll
        for (int i = 0; i < 8; i++) {
            float av = ar[i];
            acc[i][0].x += av * b0.x; acc[i][0].y += av * b0.y;
            acc[i][0].z += av * b0.z; acc[i][0].w += av * b0.w;
            acc[i][1].x += av * b1.x; acc[i][1].y += av * b1.y;
            acc[i][1].z += av * b1.z; acc[i][1].w += av * b1.w;
        }
    }
    int cbase = c0 + ct * 8;
    #pragma unroll
    for (int i = 0; i < 8; i++) {
        int r = r0 + rt * 8 + i;
        if (r >= kROWS) break;
        if (cbase < kD) {
            *(float4*)&xin[(size_t)r * kD + cbase]     = acc[i][0];
            *(float4*)&xin[(size_t)r * kD + cbase + 4] = acc[i][1];
        } else {
            *(float4*)&z[(size_t)r * kD + cbase - kD]     = acc[i][0];
            *(float4*)&z[(size_t)r * kD + cbase - kD + 4] = acc[i][1];
        }
    }
}

// ---------------- mamba out-proj GEMM + combine: [51400x192] @ [192x128pad] ----------------
__global__ __launch_bounds__(128)
void outproj_gemm(const float* __restrict__ ym, const float* __restrict__ wp,
                  const float* __restrict__ xres, float* __restrict__ out, int dir) {
    __shared__ float Al[192 * 64];  // 48 KiB
    int r0 = blockIdx.x * 64;
    int tid = threadIdx.x;
    for (int i = tid; i < 192 * 64; i += 128) {
        int m = i & 63, h = i >> 6;
        int r = r0 + m; if (r >= kROWS) r = kROWS - 1;
        Al[h * 64 + m] = ym[(size_t)r * kD + h];
    }
    __syncthreads();
    int rt = tid >> 4, ct = tid & 15;
    const float* bp = wp + ct * 8;
    float4 acc[8][2];
    #pragma unroll
    for (int i = 0; i < 8; i++) {
        acc[i][0] = make_float4(0.f, 0.f, 0.f, 0.f);
        acc[i][1] = make_float4(0.f, 0.f, 0.f, 0.f);
    }
    for (int h = 0; h < 192; h++) {
        float4 a0 = *(const float4*)&Al[h * 64 + rt * 8];
        float4 a1 = *(const float4*)&Al[h * 64 + rt * 8 + 4];
        float4 b0 = *(const float4*)&bp[h * 128];
        float4 b1 = *(const float4*)&bp[h * 128 + 4];
        float ar[8] = {a0.x, a0.y, a0.z, a0.w, a1.x, a1.y, a1.z, a1.w};
        #pragma unroll
        for (int i = 0; i < 8; i++) {
            float av = ar[i];
            acc[i][0].x += av * b0.x; acc[i][0].y += av * b0.y;
            acc[i][0].z += av * b0.z; acc[i][0].w += av * b0.w;
            acc[i][1].x += av * b1.x; acc[i][1].y += av * b1.y;
            acc[i][1].z += av * b1.z; acc[i][1].w += av * b1.w;
        }
    }
    int cbase = ct * 8;
    if (cbase >= kH) return;
    #pragma unroll
    for (int i = 0; i < 8; i++) {
        int r = r0 + rt * 8 + i;
        if (r >= kROWS) break;
        float4 v0 = acc[i][0], v1 = acc[i][1];
        size_t o = (size_t)r * kH + cbase;
        if (dir == 0) {
            float4 x0 = *(const float4*)&xres[o], x1 = *(const float4*)&xres[o + 4];
            v0.x = x0.x + 0.5f * v0.x; v0.y = x0.y + 0.5f * v0.y;
            v0.z = x0.z + 0.5f * v0.z; v0.w = x0.w + 0.5f * v0.w;
            v1.x = x1.x + 0.5f * v1.x; v1.y = x1.y + 0.5f * v1.y;
            v1.z = x1.z + 0.5f * v1.z; v1.w = x1.w + 0.5f * v1.w;
        } else {
            float4 x0 = *(const float4*)&out[o], x1 = *(const float4*)&out[o + 4];
            v0.x = x0.x + 0.5f * v0.x; v0.y = x0.y + 0.5f * v0.y;
            v0.z = x0.z + 0.5f * v0.z; v0.w = x0.w + 0.5f * v0.w;
            v1.x = x1.x + 0.5f * v1.x; v1.y = x1.y + 0.5f * v1.y;
            v1.z = x1.z + 0.5f * v1.z; v1.w = x1.w + 0.5f * v1.w;
        }
        *(float4*)&out[o] = v0;
        *(float4*)&out[o + 4] = v1;
    }
}

// ---------------- mamba depthwise conv over T + SiLU ----------------
__global__ void mconv_kernel(const float* __restrict__ xin, float* __restrict__ xc,
                             const float* __restrict__ cw, const float* __restrict__ cb, int dir) {
    int qid = blockIdx.x * blockDim.x + threadIdx.x;
    if (qid >= kROWS * 48) return;
    int r = qid / 48, d4 = (qid - r * 48) * 4;
    int bm = r / kT, t = r - bm * kT;
    float4 acc = make_float4(cb[d4], cb[d4 + 1], cb[d4 + 2], cb[d4 + 3]);
    #pragma unroll
    for (int k = 0; k < kKM; k++) {
        int ts = dir ? (t + 3 - k) : (t + k - 3);
        if (ts < 0 || ts >= kT) continue;
        float4 v = *(const float4*)&xin[((size_t)bm * kT + ts) * kD + d4];
        acc.x += v.x * cw[(d4 + 0) * kKM + k];
        acc.y += v.y * cw[(d4 + 1) * kKM + k];
        acc.z += v.z * cw[(d4 + 2) * kKM + k];
        acc.w += v.w * cw[(d4 + 3) * kKM + k];
    }
    float4 o = make_float4(silu_f(acc.x), silu_f(acc.y), silu_f(acc.z), silu_f(acc.w));
    *(float4*)&xc[(size_t)r * kD + d4] = o;
}

// ---------------- mamba x-proj GEMM: [51400x192] @ [192x48pad] ----------------
__global__ __launch_bounds__(128)
void xpproj_gemm(const float* __restrict__ xc, float* __restrict__ dbl,
                 const float* __restrict__ wpx) {
    __shared__ float Al[192 * 64];  // 48 KiB
    int r0 = blockIdx.x * 64;
    int tid = threadIdx.x;
    for (int i = tid; i < 192 * 64; i += 128) {
        int m = i & 63, h = i >> 6;
        int r = r0 + m; if (r >= kROWS) r = kROWS - 1;
        Al[h * 64 + m] = xc[(size_t)r * kD + h];
    }
    __syncthreads();
    int rt = tid >> 4, ct = tid & 15;
    const float* bp = wpx + ct * 3;
    float acc[8][3];
    #pragma unroll
    for (int i = 0; i < 8; i++)
        #pragma unroll
        for (int j = 0; j < 3; j++) acc[i][j] = 0.f;
    for (int h = 0; h < 192; h++) {
        float4 a0 = *(const float4*)&Al[h * 64 + rt * 8];
        float4 a1 = *(const float4*)&Al[h * 64 + rt * 8 + 4];
        float b0 = bp[h * kDBLP], b1 = bp[h * kDBLP + 1], b2 = bp[h * kDBLP + 2];
        float ar[8] = {a0.x, a0.y, a0.z, a0.w, a1.x, a1.y, a1.z, a1.w};
        #pragma unroll
        for (int i = 0; i < 8; i++) {
            acc[i][0] += ar[i] * b0;
            acc[i][1] += ar[i] * b1;
            acc[i][2] += ar[i] * b2;
        }
    }
    int cbase = ct * 3;
    #pragma unroll
    for (int i = 0; i < 8; i++) {
        int r = r0 + rt * 8 + i;
        if (r >= kROWS) break;
        #pragma unroll
        for (int j = 0; j < 3; j++) {
            int c = cbase + j;
            if (c < kDBL) dbl[(size_t)r * kDBL + c] = acc[i][j];
        }
    }
}

// ---------------- mamba selective scan v4: chunked + LDS-staged dbl ----------------
// One block per bm, 768 threads = (chunk c 0..3) x (d 0..191); 12 waves.
// The whole 100x38 dbl row-block is staged into LDS once (layout [t][40]:
// proj at slots 0..5, B at 8..23, C at 24..39 -- every float4 group 16B
// aligned) so the t-loop does broadcast ds_read_b128 instead of 38
// same-address global loads (v3's latency killer). Two-pass chunk scan:
// phase 1 local scan (track sdt), phase 2 4-step LDS propagation of
// incoming states, phase 3 rescan + emit.
#define HUPD(I,BV) h[I] = __expf(dt * A[I]) * h[I] + dtx * (BV);
#define YACC(I,CV) y += h[I] * (CV);

__global__ __launch_bounds__(768)
void scan_kernel(const float* __restrict__ dbl, const float* __restrict__ z,
                 float* __restrict__ xcy,
                 const float* __restrict__ A_log, const float* __restrict__ dtw,
                 const float* __restrict__ dtb, const float* __restrict__ Dp, int dir) {
    __shared__ float dsg[kT * 40];      // 16 KB
    __shared__ float hin_lds[kD * kN];  // 12.3 KB
    constexpr int CL = kT / 4;          // 25
    int bm = blockIdx.x;
    int tid = threadIdx.x;

    const float* drow = dbl + (size_t)bm * kT * kDBL;
    for (int i = tid; i < kT * kDBL; i += 768) {
        int t = i / kDBL, j = i - t * kDBL;
        int slot = (j < 6) ? j : (j + 2);
        dsg[t * 40 + slot] = drow[i];
    }
    __syncthreads();

    int c = tid / kD;                   // chunk id (wave-uniform: 192 = 3 waves)
    int d = tid - c * kD;
    int lo = c * CL, hi = lo + CL - 1;

    float A[kN];
    #pragma unroll
    for (int n = 0; n < kN; n++) A[n] = -__expf(A_log[d * kN + n]);
    float dw[kR];
    #pragma unroll
    for (int j = 0; j < kR; j++) dw[j] = dtw[d * kR + j];
    float db = dtb[d], Dv = Dp[d];

    // phase 1: local chunk scan with h_in = 0; accumulate sdt
    float h[kN];
    #pragma unroll
    for (int n = 0; n < kN; n++) h[n] = 0.f;
    float sdt = 0.f;
    for (int i = 0; i < CL; i++) {
        int t = dir ? (hi - i) : (lo + i);
        const float* row = dsg + t * 40;
        float4 q0 = *(const float4*)(row);
        float4 q1 = *(const float4*)(row + 4);
        float s = db + q0.x * dw[0] + q0.y * dw[1] + q0.z * dw[2]
                     + q0.w * dw[3] + q1.x * dw[4] + q1.y * dw[5];
        float dt = softplus_f(s);
        sdt += dt;
        float dtx = dt * xcy[((size_t)bm * kT + t) * kD + d];
        float4 B0 = *(const float4*)(row + 8);
        float4 B1 = *(const float4*)(row + 12);
        float4 B2 = *(const float4*)(row + 16);
        float4 B3 = *(const float4*)(row + 20);
        HUPD(0, B0.x) HUPD(1, B0.y) HUPD(2, B0.z) HUPD(3, B0.w)
        HUPD(4, B1.x) HUPD(5, B1.y) HUPD(6, B1.z) HUPD(7, B1.w)
        HUPD(8, B2.x) HUPD(9, B2.y) HUPD(10, B2.z) HUPD(11, B2.w)
        HUPD(12, B3.x) HUPD(13, B3.y) HUPD(14, B3.z) HUPD(15, B3.w)
    }

    // phase 2: sequential cross-chunk propagation through LDS
    for (int s = 0; s < 4; s++) {
        int cc = dir ? (3 - s) : s;
        if (c == cc) {
            #pragma unroll
            for (int n = 0; n < kN; n++) {
                float hin = (s == 0) ? 0.f : hin_lds[d * kN + n];
                hin_lds[d * kN + n] = __expf(A[n] * sdt) * hin + h[n];
                h[n] = hin;
            }
        }
        __syncthreads();
    }

    // phase 3: rescan with correct initial state, emit outputs
    for (int i = 0; i < CL; i++) {
        int t = dir ? (hi - i) : (lo + i);
        size_t rb = (size_t)bm * kT + t;
        const float* row = dsg + t * 40;
        float4 q0 = *(const float4*)(row);
        float4 q1 = *(const float4*)(row + 4);
        float s = db + q0.x * dw[0] + q0.y * dw[1] + q0.z * dw[2]
                     + q0.w * dw[3] + q1.x * dw[4] + q1.y * dw[5];
        float dt = softplus_f(s);
        float xv = xcy[rb * kD + d];
        float dtx = dt * xv;
        float4 B0 = *(const float4*)(row + 8);
        float4 B1 = *(const float4*)(row + 12);
        float4 B2 = *(const float4*)(row + 16);
        float4 B3 = *(const float4*)(row + 20);
        HUPD(0, B0.x) HUPD(1, B0.y) HUPD(2, B0.z) HUPD(3, B0.w)
        HUPD(4, B1.x) HUPD(5, B1.y) HUPD(6, B1.z) HUPD(7, B1.w)
        HUPD(8, B2.x) HUPD(9, B2.y) HUPD(10, B2.z) HUPD(11, B2.w)
        HUPD(12, B3.x) HUPD(13, B3.y) HUPD(14, B3.z) HUPD(15, B3.w)
        float4 C0 = *(const float4*)(row + 24);
        float4 C1 = *(const float4*)(row + 28);
        float4 C2 = *(const float4*)(row + 32);
        float4 C3 = *(const float4*)(row + 36);
        float y = 0.f;
        YACC(0, C0.x) YACC(1, C0.y) YACC(2, C0.z) YACC(3, C0.w)
        YACC(4, C1.x) YACC(5, C1.y) YACC(6, C1.z) YACC(7, C1.w)
        YACC(8, C2.x) YACC(9, C2.y) YACC(10, C2.z) YACC(11, C2.w)
        YACC(12, C3.x) YACC(13, C3.y) YACC(14, C3.z) YACC(15, C3.w)
        float zv = z[rb * kD + d];
        xcy[rb * kD + d] = (y + xv * Dv) * silu_f(zv);
    }
}

extern "C" void kernel_launch(void* const* d_in, const int* in_sizes, int n_in,
                              void* d_out, int out_size, void* d_ws, size_t ws_size,
                              hipStream_t stream) {
    const float* x       = (const float*)d_in[0];
    const float* ln1_g   = (const float*)d_in[1];
    const float* ln1_b   = (const float*)d_in[2];
    const float* conv1_w = (const float*)d_in[3];
    const float* conv1_b = (const float*)d_in[4];
    const float* prelu1  = (const float*)d_in[5];
    const float* lnf_g   = (const float*)d_in[6];
    const float* lnf_b   = (const float*)d_in[7];
    const float* sq_w    = (const float*)d_in[8];
    const float* sq_b    = (const float*)d_in[9];
    const float* full_w  = (const float*)d_in[10];
    const float* full_b  = (const float*)d_in[11];
    const float* unsq_w  = (const float*)d_in[12];
    const float* unsq_b  = (const float*)d_in[13];
    const float* ln2_g   = (const float*)d_in[14];
    const float* ln2_b   = (const float*)d_in[15];
    const float* conv2_w = (const float*)d_in[16];
    const float* conv2_b = (const float*)d_in[17];
    const float* prelu2  = (const float*)d_in[18];
    const float* lnm_g   = (const float*)d_in[19];
    const float* lnm_b   = (const float*)d_in[20];

    float* ws   = (float*)d_ws;
    float* xbuf = ws;
    float* xn   = ws + (size_t)kNX;
    float* bufA = ws + 2 * (size_t)kNX;          // kNM: ln-out / xin / dbl
    float* bufB = bufA + (size_t)kNM;            // kNM: s1 / z
    float* bufC = bufB + (size_t)kNM;            // kNM: s2 / xc / ymid
    float* wTs  = bufC + (size_t)kNM;
    float* in_wT[2]  = { wTs, wTs + 2 * kD * kH };                  // [96][384]
    float* out_wp[2] = { wTs + 2 * (2 * kD * kH),
                         wTs + 2 * (2 * kD * kH) + kD * 128 };      // [192][128]
    float* xp_wp[2]  = { wTs + 2 * (2 * kD * kH) + 2 * kD * 128,
                         wTs + 2 * (2 * kD * kH) + 2 * kD * 128 + kD * kDBLP }; // [192][48]

    for (int dir = 0; dir < 2; dir++) {
        int wi = 21 + dir * 9;
        const float* in_w  = (const float*)d_in[wi + 0];
        const float* xp_w  = (const float*)d_in[wi + 3];
        const float* out_w = (const float*)d_in[wi + 8];
        transpose_kernel<<<(2 * kD * kH + 255) / 256, 256, 0, stream>>>(in_w, in_wT[dir], 2 * kD, kH);
        outpad_kernel<<<(kD * 128 + 255) / 256, 256, 0, stream>>>(out_w, out_wp[dir]);
        xppad_kernel<<<(kD * kDBLP + 255) / 256, 256, 0, stream>>>(xp_w, xp_wp[dir]);
    }

    int lnGrid = (kROWS + 3) / 4;
    int nxGrid = (kNX + 255) / 256;
    dim3 fcGrid(kG, kT, kB);

    // stage 1: x = x + fconv(x)
    ln_kernel<<<lnGrid, 256, 0, stream>>>(x, bufA, ln1_g, ln1_b, kROWS);
    fconv_kernel<<<fcGrid, 256, 0, stream>>>(bufA, x, xbuf, conv1_w, conv1_b, prelu1);

    // stage 2: x = x + full(x)
    ln_kernel<<<lnGrid, 256, 0, stream>>>(xbuf, bufA, lnf_g, lnf_b, kROWS);
    squeeze_kernel<<<dim3(kB * kT, (kF + 63) / 64), 64, 0, stream>>>(bufA, bufB, sq_w, sq_b);
    fullmat_gemm<<<dim3(5, 4, kS), 256, 0, stream>>>(bufB, bufC, full_w, full_b);
    unsqueeze_kernel<<<nxGrid, 256, 0, stream>>>(bufC, xbuf, unsq_w, unsq_b);

    // stage 3: x = x + fconv(x)  (in-place: resid == out)
    ln_kernel<<<lnGrid, 256, 0, stream>>>(xbuf, bufA, ln2_g, ln2_b, kROWS);
    fconv_kernel<<<fcGrid, 256, 0, stream>>>(bufA, xbuf, xbuf, conv2_w, conv2_b, prelu2);

    // mamba input: xn = LN(x)
    ln_kernel<<<lnGrid, 256, 0, stream>>>(xbuf, xn, lnm_g, lnm_b, kROWS);

    for (int dir = 0; dir < 2; dir++) {
        int wi = 21 + dir * 9;
        const float* conv_w = (const float*)d_in[wi + 1];
        const float* conv_b = (const float*)d_in[wi + 2];
        const float* dt_w   = (const float*)d_in[wi + 4];
        const float* dt_b   = (const float*)d_in[wi + 5];
        const float* A_log  = (const float*)d_in[wi + 6];
        const float* Dp     = (const float*)d_in[wi + 7];

        inproj_gemm<<<dim3((kROWS + 63) / 64, 3), 128, 0, stream>>>(xn, in_wT[dir], bufA, bufB);
        mconv_kernel<<<(kROWS * 48 + 255) / 256, 256, 0, stream>>>(bufA, bufC, conv_w, conv_b, dir);
        xpproj_gemm<<<(kROWS + 63) / 64, 128, 0, stream>>>(bufC, bufA, xp_wp[dir]);
        scan_kernel<<<kBM, 768, 0, stream>>>(bufA, bufB, bufC, A_log, dt_w, dt_b, Dp, dir);
        outproj_gemm<<<(kROWS + 63) / 64, 128, 0, stream>>>(bufC, out_wp[dir], xbuf, (float*)d_out, dir);
    }
}

// Round 8
// 1136.530 us; speedup vs baseline: 1.2715x; 1.0520x over previous
//
#include <hip/hip_runtime.h>
#include <math.h>

// Problem constants
constexpr int kB   = 2;
constexpr int kF   = 257;   // FQ
constexpr int kT   = 100;
constexpr int kH   = 96;
constexpr int kS   = 8;
constexpr int kD   = 192;   // DIN
constexpr int kN   = 16;
constexpr int kR   = 6;
constexpr int kKF  = 5;
constexpr int kKM  = 4;
constexpr int kG   = 8;     // GROUPS
constexpr int kGC  = kH / kG;        // 12
constexpr int kBM  = kB * kF;        // 514
constexpr int kROWS = kB * kF * kT;  // 51400
constexpr int kNX  = kROWS * kH;     // 4,934,400
constexpr int kNM  = kROWS * kD;     // 9,868,800
constexpr int kDBL = kR + 2 * kN;    // 38
constexpr int kDBLP = 48;            // padded
constexpr int kPad = 68;             // LDS row pitch for staged A tiles (float4-aligned, bank-spread)

__device__ inline float wave_reduce_sum(float v) {
    for (int o = 32; o > 0; o >>= 1) v += __shfl_xor(v, o, 64);
    return v;
}
__device__ inline float silu_f(float x) { return x / (1.f + __expf(-x)); }
__device__ inline float softplus_f(float x) { return x > 20.f ? x : log1pf(__expf(x)); }

// ---------------- LayerNorm over H=96, one wave per row ----------------
__global__ void ln_kernel(const float* __restrict__ in, float* __restrict__ out,
                          const float* __restrict__ g, const float* __restrict__ b,
                          int rows) {
    int wave = threadIdx.x >> 6;
    int lane = threadIdx.x & 63;
    int r = blockIdx.x * 4 + wave;
    if (r >= rows) return;
    const float* p = in + (size_t)r * kH;
    float v0 = p[lane];
    float v1 = (lane < 32) ? p[64 + lane] : 0.f;
    float s = wave_reduce_sum(v0 + v1);
    float mean = s * (1.f / 96.f);
    float d0 = v0 - mean;
    float d1 = (lane < 32) ? (v1 - mean) : 0.f;
    float vs = wave_reduce_sum(d0 * d0 + d1 * d1);
    float rstd = rsqrtf(vs * (1.f / 96.f) + 1e-5f);
    float* q = out + (size_t)r * kH;
    q[lane] = d0 * rstd * g[lane] + b[lane];
    if (lane < 32) q[64 + lane] = d1 * rstd * g[64 + lane] + b[64 + lane];
}

// ---------------- freq-conv stage ----------------
#define FDOT(S,K) \
  acc += xw[S][0].x*wr[K][0] + xw[S][0].y*wr[K][1] + xw[S][0].z*wr[K][2] + xw[S][0].w*wr[K][3] \
       + xw[S][1].x*wr[K][4] + xw[S][1].y*wr[K][5] + xw[S][1].z*wr[K][6] + xw[S][1].w*wr[K][7] \
       + xw[S][2].x*wr[K][8] + xw[S][2].y*wr[K][9] + xw[S][2].z*wr[K][10]+ xw[S][2].w*wr[K][11];

#define FSTEP(S0,S1,S2,S3,S4)                                              \
  if (f < fmax) {                                                          \
    const float4* cp = (const float4*)(Xs + (f + 4) * 12);                 \
    xw[S4][0] = cp[0]; xw[S4][1] = cp[1]; xw[S4][2] = cp[2];               \
    float acc = bias;                                                      \
    FDOT(S0,0) FDOT(S1,1) FDOT(S2,2) FDOT(S3,3) FDOT(S4,4)                 \
    float yv = acc > 0.f ? acc : alpha_h * acc;                            \
    size_t oi = ((size_t)(bb * kF + f) * kT + tt) * kH + g12 + hh;         \
    out[oi] = resid[oi] + yv;                                              \
    f++;                                                                   \
  }

__global__ __launch_bounds__(256)
void fconv_kernel(const float* __restrict__ ln, const float* __restrict__ resid,
                  float* __restrict__ out, const float* __restrict__ w,
                  const float* __restrict__ cb, const float* __restrict__ alpha) {
    __shared__ float Xs[261 * 12];
    __shared__ float Ws[kGC * kKF * 12];  // 720
    int g = blockIdx.x, tt = blockIdx.y, bb = blockIdx.z;
    int g12 = g * 12;
    int tid = threadIdx.x;

    for (int i = tid; i < 720; i += 256) Ws[i] = w[g * 720 + i];
    for (int i = tid; i < 257 * 12; i += 256) {
        int fs = i / 12, ci = i - fs * 12;
        Xs[(fs + 2) * 12 + ci] = ln[((size_t)(bb * kF + fs) * kT + tt) * kH + g12 + ci];
    }
    if (tid < 48) {
        const int padr[4] = {0, 1, 259, 260};
        Xs[padr[tid / 12] * 12 + (tid % 12)] = 0.f;
    }
    __syncthreads();

    int lane = tid & 63, wave = tid >> 6;
    int hh = lane % 12, fi = lane / 12;
    if (fi >= 5) return;                      // duplicate-slot lanes must retire (in-place race)
    int slot = wave * 5 + fi;
    int f0 = slot * 13;
    int fmax = min(f0 + 13, kF);

    float wr[5][12];
    #pragma unroll
    for (int k = 0; k < 5; k++)
        #pragma unroll
        for (int ci = 0; ci < 12; ci++)
            wr[k][ci] = Ws[hh * 60 + ci * 5 + k];

    float bias = cb[g12 + hh];
    float alpha_h = alpha[g12 + hh];

    float4 xw[5][3];
    #pragma unroll
    for (int s = 0; s < 4; s++) {
        int row = min(f0 + s, 260);
        const float4* cp = (const float4*)(Xs + row * 12);
        xw[s][0] = cp[0]; xw[s][1] = cp[1]; xw[s][2] = cp[2];
    }
    int f = f0;
    for (int rep = 0; rep < 3; rep++) {
        FSTEP(0,1,2,3,4)
        FSTEP(1,2,3,4,0)
        FSTEP(2,3,4,0,1)
        FSTEP(3,4,0,1,2)
        FSTEP(4,0,1,2,3)
    }
}

// ---------------- full stage: squeeze H->S with SiLU ----------------
__global__ void squeeze_kernel(const float* __restrict__ ln, float* __restrict__ s1,
                               const float* __restrict__ sqw, const float* __restrict__ sqb) {
    int bt = blockIdx.x;                       // b*kT + t
    int f = blockIdx.y * 64 + threadIdx.x;
    if (f >= kF) return;
    int b = bt / kT, t = bt % kT;
    const float* row = ln + ((size_t)(b * kF + f) * kT + t) * kH;
    float acc[kS];
    for (int s = 0; s < kS; s++) acc[s] = 0.f;
    for (int h = 0; h < kH; h++) {
        float v = row[h];
        for (int s = 0; s < kS; s++) acc[s] += v * sqw[s * kH + h];
    }
    for (int s = 0; s < kS; s++)
        s1[((size_t)bt * kS + s) * kF + f] = silu_f(acc[s] + sqb[s]);
}

// ---------------- full stage: per-group GEMM over F ----------------
__global__ __launch_bounds__(256)
void fullmat_gemm(const float* __restrict__ s1, float* __restrict__ s2,
                  const float* __restrict__ fw, const float* __restrict__ fb) {
    __shared__ float As[64 * 64];  // [fk][bt]
    __shared__ float Bs[64 * 64];  // [fk][k]
    int k0 = blockIdx.x * 64, bt0 = blockIdx.y * 64, g = blockIdx.z;
    int tid = threadIdx.x;
    int rt = tid >> 4, ct = tid & 15;
    float acc[4][4];
    #pragma unroll
    for (int i = 0; i < 4; i++)
        #pragma unroll
        for (int j = 0; j < 4; j++) acc[i][j] = 0.f;

    for (int f0 = 0; f0 < kF; f0 += 64) {
        int fcnt = min(64, kF - f0);
        for (int i = tid; i < 64 * 64; i += 256) {
            int m = i & 63, fk = i >> 6;
            int bt = bt0 + m, f = f0 + fk;
            As[fk * 64 + m] = (bt < kB * kT && f < kF)
                ? s1[((size_t)bt * kS + g) * kF + f] : 0.f;
            int k = k0 + m;
            Bs[fk * 64 + m] = (k < kF && f < kF)
                ? fw[(size_t)g * kF * kF + (size_t)k * kF + f] : 0.f;
        }
        __syncthreads();
        for (int f = 0; f < fcnt; f++) {
            float4 a4 = *(const float4*)&As[f * 64 + rt * 4];
            float4 b4 = *(const float4*)&Bs[f * 64 + ct * 4];
            float ar[4] = {a4.x, a4.y, a4.z, a4.w};
            float br[4] = {b4.x, b4.y, b4.z, b4.w};
            #pragma unroll
            for (int i = 0; i < 4; i++)
                #pragma unroll
                for (int j = 0; j < 4; j++) acc[i][j] += ar[i] * br[j];
        }
        __syncthreads();
    }
    #pragma unroll
    for (int i = 0; i < 4; i++) {
        int bt = bt0 + rt * 4 + i;
        if (bt >= kB * kT) continue;
        #pragma unroll
        for (int j = 0; j < 4; j++) {
            int k = k0 + ct * 4 + j;
            if (k >= kF) continue;
            s2[((size_t)bt * kS + g) * kF + k] = acc[i][j] + fb[g * kF + k];
        }
    }
}

// ---------------- full stage: unsqueeze S->H + SiLU + residual ----------------
__global__ void unsqueeze_kernel(const float* __restrict__ s2, float* __restrict__ x,
                                 const float* __restrict__ uw, const float* __restrict__ ub) {
    int idx = blockIdx.x * blockDim.x + threadIdx.x;
    if (idx >= kNX) return;
    int h = idx % kH;
    int t = (idx / kH) % kT;
    int f = (idx / (kH * kT)) % kF;
    int b = idx / (kH * kT * kF);
    int bt = b * kT + t;
    float acc = ub[h];
    for (int s = 0; s < kS; s++)
        acc += s2[((size_t)bt * kS + s) * kF + f] * uw[h * kS + s];
    x[idx] += silu_f(acc);
}

// ---------------- small weight transpose ----------------
__global__ void transpose_kernel(const float* __restrict__ in, float* __restrict__ out,
                                 int rows, int cols) {
    int idx = blockIdx.x * blockDim.x + threadIdx.x;
    if (idx >= rows * cols) return;
    int r = idx / cols, c = idx % cols;
    out[c * rows + r] = in[idx];
}

// out_w [96][192] -> padded transpose wp [192][128] (cols >=96 zero)
__global__ void outpad_kernel(const float* __restrict__ w, float* __restrict__ wp) {
    int i = blockIdx.x * 256 + threadIdx.x;
    if (i >= kD * 128) return;
    int d = i >> 7, h = i & 127;
    wp[i] = (h < kH) ? w[h * kD + d] : 0.f;
}

// xp_w [38][192] -> padded transpose wpx [192][48] (cols >=38 zero)
__global__ void xppad_kernel(const float* __restrict__ w, float* __restrict__ wp) {
    int i = blockIdx.x * 256 + threadIdx.x;
    if (i >= kD * kDBLP) return;
    int d = i / kDBLP, n = i % kDBLP;
    wp[i] = (n < kDBL) ? w[n * kD + d] : 0.f;
}

// ---------------- mamba in-proj GEMM: [51400x96] @ [96x384] ----------------
// Staging: coalesced row-major global read, LDS write to [c][rr] with pitch 68.
__global__ __launch_bounds__(128)
void inproj_gemm(const float* __restrict__ xn, const float* __restrict__ wT,
                 float* __restrict__ xin, float* __restrict__ z) {
    __shared__ float Al[96 * kPad];  // 26.1 KB
    int r0 = blockIdx.x * 64;
    int c0 = blockIdx.y * 128;
    int tid = threadIdx.x;
    for (int j = tid; j < 64 * 96; j += 128) {
        int rr = j / 96, c = j - rr * 96;
        int r = r0 + rr; if (r >= kROWS) r = kROWS - 1;
        Al[c * kPad + rr] = xn[(size_t)r * kH + c];
    }
    __syncthreads();
    int rt = tid >> 4, ct = tid & 15;
    const float* bp = wT + c0 + ct * 8;
    float4 acc[8][2];
    #pragma unroll
    for (int i = 0; i < 8; i++) {
        acc[i][0] = make_float4(0.f, 0.f, 0.f, 0.f);
        acc[i][1] = make_float4(0.f, 0.f, 0.f, 0.f);
    }
    for (int h = 0; h < 96; h++) {
        float4 a0 = *(const float4*)&Al[h * kPad + rt * 8];
        float4 a1 = *(const float4*)&Al[h * kPad + rt * 8 + 4];
        float4 b0 = *(const float4*)&bp[(size_t)h * 384];
        float4 b1 = *(const float4*)&bp[(size_t)h * 384 + 4];
        float ar[8] = {a0.x, a0.y, a0.z, a0.w, a1.x, a1.y, a1.z, a1.w};
        #pragma unroll
        for (int i = 0; i < 8; i++) {
            float av = ar[i];
            acc[i][0].x += av * b0.x; acc[i][0].y += av * b0.y;
            acc[i][0].z += av * b0.z; acc[i][0].w += av * b0.w;
            acc[i][1].x += av * b1.x; acc[i][1].y += av * b1.y;
            acc[i][1].z += av * b1.z; acc[i][1].w += av * b1.w;
        }
    }
    int cbase = c0 + ct * 8;
    #pragma unroll
    for (int i = 0; i < 8; i++) {
        int r = r0 + rt * 8 + i;
        if (r >= kROWS) break;
        if (cbase < kD) {
            *(float4*)&xin[(size_t)r * kD + cbase]     = acc[i][0];
            *(float4*)&xin[(size_t)r * kD + cbase + 4] = acc[i][1];
        } else {
            *(float4*)&z[(size_t)r * kD + cbase - kD]     = acc[i][0];
            *(float4*)&z[(size_t)r * kD + cbase - kD + 4] = acc[i][1];
        }
    }
}

// ---------------- mamba out-proj GEMM + z-gating + combine ----------------
// Stages ym' * silu(z) (gating folded here, both read coalesced).
__global__ __launch_bounds__(128)
void outproj_gemm(const float* __restrict__ ym, const float* __restrict__ zg,
                  const float* __restrict__ wp,
                  const float* __restrict__ xres, float* __restrict__ out, int dir) {
    __shared__ float Al[192 * kPad];  // 52.2 KB
    int r0 = blockIdx.x * 64;
    int tid = threadIdx.x;
    for (int j = tid; j < 64 * 192; j += 128) {
        int rr = j / 192, c = j - rr * 192;
        int r = r0 + rr; if (r >= kROWS) r = kROWS - 1;
        size_t idx = (size_t)r * kD + c;
        Al[c * kPad + rr] = ym[idx] * silu_f(zg[idx]);
    }
    __syncthreads();
    int rt = tid >> 4, ct = tid & 15;
    const float* bp = wp + ct * 8;
    float4 acc[8][2];
    #pragma unroll
    for (int i = 0; i < 8; i++) {
        acc[i][0] = make_float4(0.f, 0.f, 0.f, 0.f);
        acc[i][1] = make_float4(0.f, 0.f, 0.f, 0.f);
    }
    for (int h = 0; h < 192; h++) {
        float4 a0 = *(const float4*)&Al[h * kPad + rt * 8];
        float4 a1 = *(const float4*)&Al[h * kPad + rt * 8 + 4];
        float4 b0 = *(const float4*)&bp[h * 128];
        float4 b1 = *(const float4*)&bp[h * 128 + 4];
        float ar[8] = {a0.x, a0.y, a0.z, a0.w, a1.x, a1.y, a1.z, a1.w};
        #pragma unroll
        for (int i = 0; i < 8; i++) {
            float av = ar[i];
            acc[i][0].x += av * b0.x; acc[i][0].y += av * b0.y;
            acc[i][0].z += av * b0.z; acc[i][0].w += av * b0.w;
            acc[i][1].x += av * b1.x; acc[i][1].y += av * b1.y;
            acc[i][1].z += av * b1.z; acc[i][1].w += av * b1.w;
        }
    }
    int cbase = ct * 8;
    if (cbase >= kH) return;
    #pragma unroll
    for (int i = 0; i < 8; i++) {
        int r = r0 + rt * 8 + i;
        if (r >= kROWS) break;
        float4 v0 = acc[i][0], v1 = acc[i][1];
        size_t o = (size_t)r * kH + cbase;
        if (dir == 0) {
            float4 x0 = *(const float4*)&xres[o], x1 = *(const float4*)&xres[o + 4];
            v0.x = x0.x + 0.5f * v0.x; v0.y = x0.y + 0.5f * v0.y;
            v0.z = x0.z + 0.5f * v0.z; v0.w = x0.w + 0.5f * v0.w;
            v1.x = x1.x + 0.5f * v1.x; v1.y = x1.y + 0.5f * v1.y;
            v1.z = x1.z + 0.5f * v1.z; v1.w = x1.w + 0.5f * v1.w;
        } else {
            float4 x0 = *(const float4*)&out[o], x1 = *(const float4*)&out[o + 4];
            v0.x = x0.x + 0.5f * v0.x; v0.y = x0.y + 0.5f * v0.y;
            v0.z = x0.z + 0.5f * v0.z; v0.w = x0.w + 0.5f * v0.w;
            v1.x = x1.x + 0.5f * v1.x; v1.y = x1.y + 0.5f * v1.y;
            v1.z = x1.z + 0.5f * v1.z; v1.w = x1.w + 0.5f * v1.w;
        }
        *(float4*)&out[o] = v0;
        *(float4*)&out[o + 4] = v1;
    }
}

// ---------------- mamba depthwise conv over T + SiLU ----------------
__global__ void mconv_kernel(const float* __restrict__ xin, float* __restrict__ xc,
                             const float* __restrict__ cw, const float* __restrict__ cb, int dir) {
    int qid = blockIdx.x * blockDim.x + threadIdx.x;
    if (qid >= kROWS * 48) return;
    int r = qid / 48, d4 = (qid - r * 48) * 4;
    int bm = r / kT, t = r - bm * kT;
    float4 acc = make_float4(cb[d4], cb[d4 + 1], cb[d4 + 2], cb[d4 + 3]);
    #pragma unroll
    for (int k = 0; k < kKM; k++) {
        int ts = dir ? (t + 3 - k) : (t + k - 3);
        if (ts < 0 || ts >= kT) continue;
        float4 v = *(const float4*)&xin[((size_t)bm * kT + ts) * kD + d4];
        acc.x += v.x * cw[(d4 + 0) * kKM + k];
        acc.y += v.y * cw[(d4 + 1) * kKM + k];
        acc.z += v.z * cw[(d4 + 2) * kKM + k];
        acc.w += v.w * cw[(d4 + 3) * kKM + k];
    }
    float4 o = make_float4(silu_f(acc.x), silu_f(acc.y), silu_f(acc.z), silu_f(acc.w));
    *(float4*)&xc[(size_t)r * kD + d4] = o;
}

// ---------------- mamba x-proj GEMM: [51400x192] @ [192x48pad] ----------------
__global__ __launch_bounds__(128)
void xpproj_gemm(const float* __restrict__ xc, float* __restrict__ dbl,
                 const float* __restrict__ wpx) {
    __shared__ float Al[192 * kPad];  // 52.2 KB
    int r0 = blockIdx.x * 64;
    int tid = threadIdx.x;
    for (int j = tid; j < 64 * 192; j += 128) {
        int rr = j / 192, c = j - rr * 192;
        int r = r0 + rr; if (r >= kROWS) r = kROWS - 1;
        Al[c * kPad + rr] = xc[(size_t)r * kD + c];
    }
    __syncthreads();
    int rt = tid >> 4, ct = tid & 15;
    const float* bp = wpx + ct * 3;
    float acc[8][3];
    #pragma unroll
    for (int i = 0; i < 8; i++)
        #pragma unroll
        for (int j = 0; j < 3; j++) acc[i][j] = 0.f;
    for (int h = 0; h < 192; h++) {
        float4 a0 = *(const float4*)&Al[h * kPad + rt * 8];
        float4 a1 = *(const float4*)&Al[h * kPad + rt * 8 + 4];
        float b0 = bp[h * kDBLP], b1 = bp[h * kDBLP + 1], b2 = bp[h * kDBLP + 2];
        float ar[8] = {a0.x, a0.y, a0.z, a0.w, a1.x, a1.y, a1.z, a1.w};
        #pragma unroll
        for (int i = 0; i < 8; i++) {
            acc[i][0] += ar[i] * b0;
            acc[i][1] += ar[i] * b1;
            acc[i][2] += ar[i] * b2;
        }
    }
    int cbase = ct * 3;
    #pragma unroll
    for (int i = 0; i < 8; i++) {
        int r = r0 + rt * 8 + i;
        if (r >= kROWS) break;
        #pragma unroll
        for (int j = 0; j < 3; j++) {
            int c = cbase + j;
            if (c < kDBL) dbl[(size_t)r * kDBL + c] = acc[i][j];
        }
    }
}

// ---------------- mamba selective scan v5: single-pass + 4-deep prefetch ----------------
// R4 structure (thread per (bm,d), 100 serial steps, dbl reads are wave-
// uniform -> scalarized by compiler). Changes vs R4: (a) t-loop grouped by 4,
// all 4 xv loads issued before compute -> 4x outstanding memory; (b) z-gating
// moved to outproj (one fewer load stream here). Writes UNGATED ym' = y + xv*D.
__global__ __launch_bounds__(192)
void scan_kernel(const float* __restrict__ dbl, float* __restrict__ xcy,
                 const float* __restrict__ A_log, const float* __restrict__ dtw,
                 const float* __restrict__ dtb, const float* __restrict__ Dp, int dir) {
    int bm = blockIdx.x;
    int d = threadIdx.x;
    float A[kN], h[kN], dw[kR];
    #pragma unroll
    for (int n = 0; n < kN; n++) { A[n] = -__expf(A_log[d * kN + n]); h[n] = 0.f; }
    #pragma unroll
    for (int j = 0; j < kR; j++) dw[j] = dtw[d * kR + j];
    float db = dtb[d], Dv = Dp[d];

    const float* base = dbl + (size_t)bm * kT * kDBL;
    float* xrow = xcy + (size_t)bm * kT * kD + d;

    for (int tb = 0; tb < kT; tb += 4) {
        int ts[4];
        float xv[4];
        #pragma unroll
        for (int u = 0; u < 4; u++) {
            ts[u] = dir ? (kT - 1 - (tb + u)) : (tb + u);
            xv[u] = xrow[(size_t)ts[u] * kD];
        }
        #pragma unroll
        for (int u = 0; u < 4; u++) {
            const float* dr = base + ts[u] * kDBL;
            float s = db + dr[0] * dw[0] + dr[1] * dw[1] + dr[2] * dw[2]
                         + dr[3] * dw[3] + dr[4] * dw[4] + dr[5] * dw[5];
            float dt = softplus_f(s);
            float dtx = dt * xv[u];
            float y = 0.f;
            #pragma unroll
            for (int n = 0; n < kN; n++) {
                h[n] = __expf(dt * A[n]) * h[n] + dtx * dr[kR + n];
                y += h[n] * dr[kR + kN + n];
            }
            xrow[(size_t)ts[u] * kD] = y + xv[u] * Dv;
        }
    }
}

extern "C" void kernel_launch(void* const* d_in, const int* in_sizes, int n_in,
                              void* d_out, int out_size, void* d_ws, size_t ws_size,
                              hipStream_t stream) {
    const float* x       = (const float*)d_in[0];
    const float* ln1_g   = (const float*)d_in[1];
    const float* ln1_b   = (const float*)d_in[2];
    const float* conv1_w = (const float*)d_in[3];
    const float* conv1_b = (const float*)d_in[4];
    const float* prelu1  = (const float*)d_in[5];
    const float* lnf_g   = (const float*)d_in[6];
    const float* lnf_b   = (const float*)d_in[7];
    const float* sq_w    = (const float*)d_in[8];
    const float* sq_b    = (const float*)d_in[9];
    const float* full_w  = (const float*)d_in[10];
    const float* full_b  = (const float*)d_in[11];
    const float* unsq_w  = (const float*)d_in[12];
    const float* unsq_b  = (const float*)d_in[13];
    const float* ln2_g   = (const float*)d_in[14];
    const float* ln2_b   = (const float*)d_in[15];
    const float* conv2_w = (const float*)d_in[16];
    const float* conv2_b = (const float*)d_in[17];
    const float* prelu2  = (const float*)d_in[18];
    const float* lnm_g   = (const float*)d_in[19];
    const float* lnm_b   = (const float*)d_in[20];

    float* ws   = (float*)d_ws;
    float* xbuf = ws;
    float* xn   = ws + (size_t)kNX;
    float* bufA = ws + 2 * (size_t)kNX;          // kNM: ln-out / xin / dbl
    float* bufB = bufA + (size_t)kNM;            // kNM: s1 / z
    float* bufC = bufB + (size_t)kNM;            // kNM: s2 / xc / ym'
    float* wTs  = bufC + (size_t)kNM;
    float* in_wT[2]  = { wTs, wTs + 2 * kD * kH };                  // [96][384]
    float* out_wp[2] = { wTs + 2 * (2 * kD * kH),
                         wTs + 2 * (2 * kD * kH) + kD * 128 };      // [192][128]
    float* xp_wp[2]  = { wTs + 2 * (2 * kD * kH) + 2 * kD * 128,
                         wTs + 2 * (2 * kD * kH) + 2 * kD * 128 + kD * kDBLP }; // [192][48]

    for (int dir = 0; dir < 2; dir++) {
        int wi = 21 + dir * 9;
        const float* in_w  = (const float*)d_in[wi + 0];
        const float* xp_w  = (const float*)d_in[wi + 3];
        const float* out_w = (const float*)d_in[wi + 8];
        transpose_kernel<<<(2 * kD * kH + 255) / 256, 256, 0, stream>>>(in_w, in_wT[dir], 2 * kD, kH);
        outpad_kernel<<<(kD * 128 + 255) / 256, 256, 0, stream>>>(out_w, out_wp[dir]);
        xppad_kernel<<<(kD * kDBLP + 255) / 256, 256, 0, stream>>>(xp_w, xp_wp[dir]);
    }

    int lnGrid = (kROWS + 3) / 4;
    int nxGrid = (kNX + 255) / 256;
    dim3 fcGrid(kG, kT, kB);

    // stage 1: x = x + fconv(x)
    ln_kernel<<<lnGrid, 256, 0, stream>>>(x, bufA, ln1_g, ln1_b, kROWS);
    fconv_kernel<<<fcGrid, 256, 0, stream>>>(bufA, x, xbuf, conv1_w, conv1_b, prelu1);

    // stage 2: x = x + full(x)
    ln_kernel<<<lnGrid, 256, 0, stream>>>(xbuf, bufA, lnf_g, lnf_b, kROWS);
    squeeze_kernel<<<dim3(kB * kT, (kF + 63) / 64), 64, 0, stream>>>(bufA, bufB, sq_w, sq_b);
    fullmat_gemm<<<dim3(5, 4, kS), 256, 0, stream>>>(bufB, bufC, full_w, full_b);
    unsqueeze_kernel<<<nxGrid, 256, 0, stream>>>(bufC, xbuf, unsq_w, unsq_b);

    // stage 3: x = x + fconv(x)  (in-place: resid == out)
    ln_kernel<<<lnGrid, 256, 0, stream>>>(xbuf, bufA, ln2_g, ln2_b, kROWS);
    fconv_kernel<<<fcGrid, 256, 0, stream>>>(bufA, xbuf, xbuf, conv2_w, conv2_b, prelu2);

    // mamba input: xn = LN(x)
    ln_kernel<<<lnGrid, 256, 0, stream>>>(xbuf, xn, lnm_g, lnm_b, kROWS);

    for (int dir = 0; dir < 2; dir++) {
        int wi = 21 + dir * 9;
        const float* conv_w = (const float*)d_in[wi + 1];
        const float* conv_b = (const float*)d_in[wi + 2];
        const float* dt_w   = (const float*)d_in[wi + 4];
        const float* dt_b   = (const float*)d_in[wi + 5];
        const float* A_log  = (const float*)d_in[wi + 6];
        const float* Dp     = (const float*)d_in[wi + 7];

        inproj_gemm<<<dim3((kROWS + 63) / 64, 3), 128, 0, stream>>>(xn, in_wT[dir], bufA, bufB);
        mconv_kernel<<<(kROWS * 48 + 255) / 256, 256, 0, stream>>>(bufA, bufC, conv_w, conv_b, dir);
        xpproj_gemm<<<(kROWS + 63) / 64, 128, 0, stream>>>(bufC, bufA, xp_wp[dir]);
        scan_kernel<<<kBM, kD, 0, stream>>>(bufA, bufC, A_log, dt_w, dt_b, Dp, dir);
        outproj_gemm<<<(kROWS + 63) / 64, 128, 0, stream>>>(bufC, bufB, out_wp[dir], xbuf, (float*)d_out, dir);
    }
}

// Round 9
// 946.100 us; speedup vs baseline: 1.5274x; 1.2013x over previous
//
#include <hip/hip_runtime.h>
#include <math.h>

// Problem constants
constexpr int kB   = 2;
constexpr int kF   = 257;   // FQ
constexpr int kT   = 100;
constexpr int kH   = 96;
constexpr int kS   = 8;
constexpr int kD   = 192;   // DIN
constexpr int kN   = 16;
constexpr int kR   = 6;
constexpr int kKF  = 5;
constexpr int kKM  = 4;
constexpr int kG   = 8;     // GROUPS
constexpr int kGC  = kH / kG;        // 12
constexpr int kBM  = kB * kF;        // 514
constexpr int kROWS = kB * kF * kT;  // 51400
constexpr int kNX  = kROWS * kH;     // 4,934,400
constexpr int kNM  = kROWS * kD;     // 9,868,800
constexpr int kDBL = kR + 2 * kN;    // 38
constexpr int kDBLP = 48;            // padded

__device__ inline float wave_reduce_sum(float v) {
    for (int o = 32; o > 0; o >>= 1) v += __shfl_xor(v, o, 64);
    return v;
}
__device__ inline float silu_f(float x) { return x / (1.f + __expf(-x)); }
__device__ inline float softplus_f(float x) { return x > 20.f ? x : log1pf(__expf(x)); }

// ---------------- LayerNorm over H=96, one wave per row ----------------
__global__ void ln_kernel(const float* __restrict__ in, float* __restrict__ out,
                          const float* __restrict__ g, const float* __restrict__ b,
                          int rows) {
    int wave = threadIdx.x >> 6;
    int lane = threadIdx.x & 63;
    int r = blockIdx.x * 4 + wave;
    if (r >= rows) return;
    const float* p = in + (size_t)r * kH;
    float v0 = p[lane];
    float v1 = (lane < 32) ? p[64 + lane] : 0.f;
    float s = wave_reduce_sum(v0 + v1);
    float mean = s * (1.f / 96.f);
    float d0 = v0 - mean;
    float d1 = (lane < 32) ? (v1 - mean) : 0.f;
    float vs = wave_reduce_sum(d0 * d0 + d1 * d1);
    float rstd = rsqrtf(vs * (1.f / 96.f) + 1e-5f);
    float* q = out + (size_t)r * kH;
    q[lane] = d0 * rstd * g[lane] + b[lane];
    if (lane < 32) q[64 + lane] = d1 * rstd * g[64 + lane] + b[64 + lane];
}

// ---------------- freq-conv stage ----------------
#define FDOT(S,K) \
  acc += xw[S][0].x*wr[K][0] + xw[S][0].y*wr[K][1] + xw[S][0].z*wr[K][2] + xw[S][0].w*wr[K][3] \
       + xw[S][1].x*wr[K][4] + xw[S][1].y*wr[K][5] + xw[S][1].z*wr[K][6] + xw[S][1].w*wr[K][7] \
       + xw[S][2].x*wr[K][8] + xw[S][2].y*wr[K][9] + xw[S][2].z*wr[K][10]+ xw[S][2].w*wr[K][11];

#define FSTEP(S0,S1,S2,S3,S4)                                              \
  if (f < fmax) {                                                          \
    const float4* cp = (const float4*)(Xs + (f + 4) * 12);                 \
    xw[S4][0] = cp[0]; xw[S4][1] = cp[1]; xw[S4][2] = cp[2];               \
    float acc = bias;                                                      \
    FDOT(S0,0) FDOT(S1,1) FDOT(S2,2) FDOT(S3,3) FDOT(S4,4)                 \
    float yv = acc > 0.f ? acc : alpha_h * acc;                            \
    size_t oi = ((size_t)(bb * kF + f) * kT + tt) * kH + g12 + hh;         \
    out[oi] = resid[oi] + yv;                                              \
    f++;                                                                   \
  }

__global__ __launch_bounds__(256)
void fconv_kernel(const float* __restrict__ ln, const float* __restrict__ resid,
                  float* __restrict__ out, const float* __restrict__ w,
                  const float* __restrict__ cb, const float* __restrict__ alpha) {
    __shared__ float Xs[261 * 12];
    __shared__ float Ws[kGC * kKF * 12];  // 720
    int g = blockIdx.x, tt = blockIdx.y, bb = blockIdx.z;
    int g12 = g * 12;
    int tid = threadIdx.x;

    for (int i = tid; i < 720; i += 256) Ws[i] = w[g * 720 + i];
    for (int i = tid; i < 257 * 12; i += 256) {
        int fs = i / 12, ci = i - fs * 12;
        Xs[(fs + 2) * 12 + ci] = ln[((size_t)(bb * kF + fs) * kT + tt) * kH + g12 + ci];
    }
    if (tid < 48) {
        const int padr[4] = {0, 1, 259, 260};
        Xs[padr[tid / 12] * 12 + (tid % 12)] = 0.f;
    }
    __syncthreads();

    int lane = tid & 63, wave = tid >> 6;
    int hh = lane % 12, fi = lane / 12;
    if (fi >= 5) return;                      // duplicate-slot lanes must retire (in-place race)
    int slot = wave * 5 + fi;
    int f0 = slot * 13;
    int fmax = min(f0 + 13, kF);

    float wr[5][12];
    #pragma unroll
    for (int k = 0; k < 5; k++)
        #pragma unroll
        for (int ci = 0; ci < 12; ci++)
            wr[k][ci] = Ws[hh * 60 + ci * 5 + k];

    float bias = cb[g12 + hh];
    float alpha_h = alpha[g12 + hh];

    float4 xw[5][3];
    #pragma unroll
    for (int s = 0; s < 4; s++) {
        int row = min(f0 + s, 260);
        const float4* cp = (const float4*)(Xs + row * 12);
        xw[s][0] = cp[0]; xw[s][1] = cp[1]; xw[s][2] = cp[2];
    }
    int f = f0;
    for (int rep = 0; rep < 3; rep++) {
        FSTEP(0,1,2,3,4)
        FSTEP(1,2,3,4,0)
        FSTEP(2,3,4,0,1)
        FSTEP(3,4,0,1,2)
        FSTEP(4,0,1,2,3)
    }
}

// ---------------- full stage: squeeze H->S with SiLU ----------------
__global__ void squeeze_kernel(const float* __restrict__ ln, float* __restrict__ s1,
                               const float* __restrict__ sqw, const float* __restrict__ sqb) {
    int bt = blockIdx.x;                       // b*kT + t
    int f = blockIdx.y * 64 + threadIdx.x;
    if (f >= kF) return;
    int b = bt / kT, t = bt % kT;
    const float* row = ln + ((size_t)(b * kF + f) * kT + t) * kH;
    float acc[kS];
    for (int s = 0; s < kS; s++) acc[s] = 0.f;
    for (int h = 0; h < kH; h++) {
        float v = row[h];
        for (int s = 0; s < kS; s++) acc[s] += v * sqw[s * kH + h];
    }
    for (int s = 0; s < kS; s++)
        s1[((size_t)bt * kS + s) * kF + f] = silu_f(acc[s] + sqb[s]);
}

// ---------------- full stage: per-group GEMM over F ----------------
__global__ __launch_bounds__(256)
void fullmat_gemm(const float* __restrict__ s1, float* __restrict__ s2,
                  const float* __restrict__ fw, const float* __restrict__ fb) {
    __shared__ float As[64 * 64];  // [fk][bt]
    __shared__ float Bs[64 * 64];  // [fk][k]
    int k0 = blockIdx.x * 64, bt0 = blockIdx.y * 64, g = blockIdx.z;
    int tid = threadIdx.x;
    int rt = tid >> 4, ct = tid & 15;
    float acc[4][4];
    #pragma unroll
    for (int i = 0; i < 4; i++)
        #pragma unroll
        for (int j = 0; j < 4; j++) acc[i][j] = 0.f;

    for (int f0 = 0; f0 < kF; f0 += 64) {
        int fcnt = min(64, kF - f0);
        for (int i = tid; i < 64 * 64; i += 256) {
            int m = i & 63, fk = i >> 6;
            int bt = bt0 + m, f = f0 + fk;
            As[fk * 64 + m] = (bt < kB * kT && f < kF)
                ? s1[((size_t)bt * kS + g) * kF + f] : 0.f;
            int k = k0 + m;
            Bs[fk * 64 + m] = (k < kF && f < kF)
                ? fw[(size_t)g * kF * kF + (size_t)k * kF + f] : 0.f;
        }
        __syncthreads();
        for (int f = 0; f < fcnt; f++) {
            float4 a4 = *(const float4*)&As[f * 64 + rt * 4];
            float4 b4 = *(const float4*)&Bs[f * 64 + ct * 4];
            float ar[4] = {a4.x, a4.y, a4.z, a4.w};
            float br[4] = {b4.x, b4.y, b4.z, b4.w};
            #pragma unroll
            for (int i = 0; i < 4; i++)
                #pragma unroll
                for (int j = 0; j < 4; j++) acc[i][j] += ar[i] * br[j];
        }
        __syncthreads();
    }
    #pragma unroll
    for (int i = 0; i < 4; i++) {
        int bt = bt0 + rt * 4 + i;
        if (bt >= kB * kT) continue;
        #pragma unroll
        for (int j = 0; j < 4; j++) {
            int k = k0 + ct * 4 + j;
            if (k >= kF) continue;
            s2[((size_t)bt * kS + g) * kF + k] = acc[i][j] + fb[g * kF + k];
        }
    }
}

// ---------------- full stage: unsqueeze S->H + SiLU + residual ----------------
__global__ void unsqueeze_kernel(const float* __restrict__ s2, float* __restrict__ x,
                                 const float* __restrict__ uw, const float* __restrict__ ub) {
    int idx = blockIdx.x * blockDim.x + threadIdx.x;
    if (idx >= kNX) return;
    int h = idx % kH;
    int t = (idx / kH) % kT;
    int f = (idx / (kH * kT)) % kF;
    int b = idx / (kH * kT * kF);
    int bt = b * kT + t;
    float acc = ub[h];
    for (int s = 0; s < kS; s++)
        acc += s2[((size_t)bt * kS + s) * kF + f] * uw[h * kS + s];
    x[idx] += silu_f(acc);
}

// ---------------- small weight transpose ----------------
__global__ void transpose_kernel(const float* __restrict__ in, float* __restrict__ out,
                                 int rows, int cols) {
    int idx = blockIdx.x * blockDim.x + threadIdx.x;
    if (idx >= rows * cols) return;
    int r = idx / cols, c = idx % cols;
    out[c * rows + r] = in[idx];
}

// xp_w [38][192] -> padded transpose wpx [192][48] (cols >=38 zero)
__global__ void xppad_kernel(const float* __restrict__ w, float* __restrict__ wp) {
    int i = blockIdx.x * 256 + threadIdx.x;
    if (i >= kD * kDBLP) return;
    int d = i / kDBLP, n = i % kDBLP;
    wp[i] = (n < kDBL) ? w[n * kD + d] : 0.f;
}

// ---------------- mamba in-proj GEMM: [51400x96] @ [96x384] ----------------
// 256 thr, 64 rows x 128 cols per block. A row-major in LDS (pitch 96, %32==0:
// compute reads are 2-addr same-bank broadcasts = free 2-way). Per-thread 8x4.
__global__ __launch_bounds__(256)
void inproj_gemm(const float* __restrict__ xn, const float* __restrict__ wT,
                 float* __restrict__ xin, float* __restrict__ z) {
    __shared__ float Al[64 * 96];  // 24.6 KB
    int r0 = blockIdx.x * 64;
    int c0 = blockIdx.y * 128;
    int tid = threadIdx.x;
    for (int i = tid; i < 64 * 24; i += 256) {
        int rr = i / 24, cq = i - rr * 24;
        int r = r0 + rr; if (r >= kROWS) r = kROWS - 1;
        *(float4*)&Al[rr * 96 + cq * 4] = *(const float4*)&xn[(size_t)r * kH + cq * 4];
    }
    __syncthreads();
    int rt = tid >> 5, ct = tid & 31;
    const float* ap = Al + rt * 8 * 96;
    const float* bp = wT + c0 + ct * 4;
    float4 acc[8];
    #pragma unroll
    for (int i = 0; i < 8; i++) acc[i] = make_float4(0.f, 0.f, 0.f, 0.f);
    for (int h = 0; h < 96; h++) {
        float4 b = *(const float4*)&bp[(size_t)h * 384];
        #pragma unroll
        for (int i = 0; i < 8; i++) {
            float av = ap[i * 96 + h];
            acc[i].x += av * b.x; acc[i].y += av * b.y;
            acc[i].z += av * b.z; acc[i].w += av * b.w;
        }
    }
    int cbase = c0 + ct * 4;
    #pragma unroll
    for (int i = 0; i < 8; i++) {
        int r = r0 + rt * 8 + i;
        if (r >= kROWS) break;
        if (cbase < kD) *(float4*)&xin[(size_t)r * kD + cbase] = acc[i];
        else            *(float4*)&z[(size_t)r * kD + cbase - kD] = acc[i];
    }
}

// ---------------- mamba out-proj GEMM + z-gating + combine ----------------
// 256 thr, 64 rows x 96 cols, K=192. A = ym*silu(z) staged row-major
// (pitch 192, conflict-free). W^T is [192][96] unpadded. Per-thread 8x3.
__global__ __launch_bounds__(256)
void outproj_gemm(const float* __restrict__ ym, const float* __restrict__ zg,
                  const float* __restrict__ wpT,
                  const float* __restrict__ xres, float* __restrict__ out, int dir) {
    __shared__ float Al[64 * 192];  // 49.2 KB
    int r0 = blockIdx.x * 64;
    int tid = threadIdx.x;
    for (int i = tid; i < 64 * 48; i += 256) {
        int rr = i / 48, cq = i - rr * 48;
        int r = r0 + rr; if (r >= kROWS) r = kROWS - 1;
        size_t gidx = (size_t)r * kD + cq * 4;
        float4 a = *(const float4*)&ym[gidx];
        float4 g4 = *(const float4*)&zg[gidx];
        a.x *= silu_f(g4.x); a.y *= silu_f(g4.y);
        a.z *= silu_f(g4.z); a.w *= silu_f(g4.w);
        *(float4*)&Al[rr * 192 + cq * 4] = a;
    }
    __syncthreads();
    int rt = tid >> 5, ct = tid & 31;   // cols 3*ct .. 3*ct+2
    const float* ap = Al + rt * 8 * 192;
    const float* bp = wpT + ct * 3;
    float acc[8][3];
    #pragma unroll
    for (int i = 0; i < 8; i++) { acc[i][0] = 0.f; acc[i][1] = 0.f; acc[i][2] = 0.f; }
    for (int h = 0; h < 192; h++) {
        float b0 = bp[h * 96], b1 = bp[h * 96 + 1], b2 = bp[h * 96 + 2];
        #pragma unroll
        for (int i = 0; i < 8; i++) {
            float av = ap[i * 192 + h];
            acc[i][0] += av * b0; acc[i][1] += av * b1; acc[i][2] += av * b2;
        }
    }
    int cbase = ct * 3;
    #pragma unroll
    for (int i = 0; i < 8; i++) {
        int r = r0 + rt * 8 + i;
        if (r >= kROWS) break;
        size_t o = (size_t)r * kH + cbase;
        #pragma unroll
        for (int j = 0; j < 3; j++) {
            float base = dir ? out[o + j] : xres[o + j];
            out[o + j] = base + 0.5f * acc[i][j];
        }
    }
}

// ---------------- mamba depthwise conv over T + SiLU ----------------
__global__ void mconv_kernel(const float* __restrict__ xin, float* __restrict__ xc,
                             const float* __restrict__ cw, const float* __restrict__ cb, int dir) {
    int qid = blockIdx.x * blockDim.x + threadIdx.x;
    if (qid >= kROWS * 48) return;
    int r = qid / 48, d4 = (qid - r * 48) * 4;
    int bm = r / kT, t = r - bm * kT;
    float4 acc = make_float4(cb[d4], cb[d4 + 1], cb[d4 + 2], cb[d4 + 3]);
    #pragma unroll
    for (int k = 0; k < kKM; k++) {
        int ts = dir ? (t + 3 - k) : (t + k - 3);
        if (ts < 0 || ts >= kT) continue;
        float4 v = *(const float4*)&xin[((size_t)bm * kT + ts) * kD + d4];
        acc.x += v.x * cw[(d4 + 0) * kKM + k];
        acc.y += v.y * cw[(d4 + 1) * kKM + k];
        acc.z += v.z * cw[(d4 + 2) * kKM + k];
        acc.w += v.w * cw[(d4 + 3) * kKM + k];
    }
    float4 o = make_float4(silu_f(acc.x), silu_f(acc.y), silu_f(acc.z), silu_f(acc.w));
    *(float4*)&xc[(size_t)r * kD + d4] = o;
}

// ---------------- mamba x-proj GEMM: [51400x192] @ [192x48pad] ----------------
// Same template as outproj: 256 thr, 64 rows, A row-major pitch 192.
// Per-thread 8 rows x 2 cols; ct<24 covers the 48 padded cols.
__global__ __launch_bounds__(256)
void xpproj_gemm(const float* __restrict__ xc, float* __restrict__ dbl,
                 const float* __restrict__ wpx) {
    __shared__ float Al[64 * 192];  // 49.2 KB
    int r0 = blockIdx.x * 64;
    int tid = threadIdx.x;
    for (int i = tid; i < 64 * 48; i += 256) {
        int rr = i / 48, cq = i - rr * 48;
        int r = r0 + rr; if (r >= kROWS) r = kROWS - 1;
        *(float4*)&Al[rr * 192 + cq * 4] = *(const float4*)&xc[(size_t)r * kD + cq * 4];
    }
    __syncthreads();
    int rt = tid >> 5, ct = tid & 31;
    if (ct >= 24) return;               // 48 cols / 2 per thread
    const float* ap = Al + rt * 8 * 192;
    const float* bp = wpx + ct * 2;
    float acc[8][2];
    #pragma unroll
    for (int i = 0; i < 8; i++) { acc[i][0] = 0.f; acc[i][1] = 0.f; }
    for (int h = 0; h < 192; h++) {
        float b0 = bp[h * kDBLP], b1 = bp[h * kDBLP + 1];
        #pragma unroll
        for (int i = 0; i < 8; i++) {
            float av = ap[i * 192 + h];
            acc[i][0] += av * b0; acc[i][1] += av * b1;
        }
    }
    int cbase = ct * 2;
    #pragma unroll
    for (int i = 0; i < 8; i++) {
        int r = r0 + rt * 8 + i;
        if (r >= kROWS) break;
        #pragma unroll
        for (int j = 0; j < 2; j++) {
            int c = cbase + j;
            if (c < kDBL) dbl[(size_t)r * kDBL + c] = acc[i][j];
        }
    }
}

// ---------------- mamba selective scan v5: single-pass + 4-deep prefetch ----------------
__global__ __launch_bounds__(192)
void scan_kernel(const float* __restrict__ dbl, float* __restrict__ xcy,
                 const float* __restrict__ A_log, const float* __restrict__ dtw,
                 const float* __restrict__ dtb, const float* __restrict__ Dp, int dir) {
    int bm = blockIdx.x;
    int d = threadIdx.x;
    float A[kN], h[kN], dw[kR];
    #pragma unroll
    for (int n = 0; n < kN; n++) { A[n] = -__expf(A_log[d * kN + n]); h[n] = 0.f; }
    #pragma unroll
    for (int j = 0; j < kR; j++) dw[j] = dtw[d * kR + j];
    float db = dtb[d], Dv = Dp[d];

    const float* base = dbl + (size_t)bm * kT * kDBL;
    float* xrow = xcy + (size_t)bm * kT * kD + d;

    for (int tb = 0; tb < kT; tb += 4) {
        int ts[4];
        float xv[4];
        #pragma unroll
        for (int u = 0; u < 4; u++) {
            ts[u] = dir ? (kT - 1 - (tb + u)) : (tb + u);
            xv[u] = xrow[(size_t)ts[u] * kD];
        }
        #pragma unroll
        for (int u = 0; u < 4; u++) {
            const float* dr = base + ts[u] * kDBL;
            float s = db + dr[0] * dw[0] + dr[1] * dw[1] + dr[2] * dw[2]
                         + dr[3] * dw[3] + dr[4] * dw[4] + dr[5] * dw[5];
            float dt = softplus_f(s);
            float dtx = dt * xv[u];
            float y = 0.f;
            #pragma unroll
            for (int n = 0; n < kN; n++) {
                h[n] = __expf(dt * A[n]) * h[n] + dtx * dr[kR + n];
                y += h[n] * dr[kR + kN + n];
            }
            xrow[(size_t)ts[u] * kD] = y + xv[u] * Dv;
        }
    }
}

extern "C" void kernel_launch(void* const* d_in, const int* in_sizes, int n_in,
                              void* d_out, int out_size, void* d_ws, size_t ws_size,
                              hipStream_t stream) {
    const float* x       = (const float*)d_in[0];
    const float* ln1_g   = (const float*)d_in[1];
    const float* ln1_b   = (const float*)d_in[2];
    const float* conv1_w = (const float*)d_in[3];
    const float* conv1_b = (const float*)d_in[4];
    const float* prelu1  = (const float*)d_in[5];
    const float* lnf_g   = (const float*)d_in[6];
    const float* lnf_b   = (const float*)d_in[7];
    const float* sq_w    = (const float*)d_in[8];
    const float* sq_b    = (const float*)d_in[9];
    const float* full_w  = (const float*)d_in[10];
    const float* full_b  = (const float*)d_in[11];
    const float* unsq_w  = (const float*)d_in[12];
    const float* unsq_b  = (const float*)d_in[13];
    const float* ln2_g   = (const float*)d_in[14];
    const float* ln2_b   = (const float*)d_in[15];
    const float* conv2_w = (const float*)d_in[16];
    const float* conv2_b = (const float*)d_in[17];
    const float* prelu2  = (const float*)d_in[18];
    const float* lnm_g   = (const float*)d_in[19];
    const float* lnm_b   = (const float*)d_in[20];

    float* ws   = (float*)d_ws;
    float* xbuf = ws;
    float* xn   = ws + (size_t)kNX;
    float* bufA = ws + 2 * (size_t)kNX;          // kNM: ln-out / xin / dbl
    float* bufB = bufA + (size_t)kNM;            // kNM: s1 / z
    float* bufC = bufB + (size_t)kNM;            // kNM: s2 / xc / ym'
    float* wTs  = bufC + (size_t)kNM;
    float* in_wT[2]  = { wTs, wTs + 2 * kD * kH };                  // [96][384]
    float* out_wp[2] = { wTs + 2 * (2 * kD * kH),
                         wTs + 2 * (2 * kD * kH) + kD * kH };       // [192][96]
    float* xp_wp[2]  = { wTs + 2 * (2 * kD * kH) + 2 * kD * kH,
                         wTs + 2 * (2 * kD * kH) + 2 * kD * kH + kD * kDBLP }; // [192][48]

    for (int dir = 0; dir < 2; dir++) {
        int wi = 21 + dir * 9;
        const float* in_w  = (const float*)d_in[wi + 0];
        const float* xp_w  = (const float*)d_in[wi + 3];
        const float* out_w = (const float*)d_in[wi + 8];
        transpose_kernel<<<(2 * kD * kH + 255) / 256, 256, 0, stream>>>(in_w, in_wT[dir], 2 * kD, kH);
        transpose_kernel<<<(kH * kD + 255) / 256, 256, 0, stream>>>(out_w, out_wp[dir], kH, kD);
        xppad_kernel<<<(kD * kDBLP + 255) / 256, 256, 0, stream>>>(xp_w, xp_wp[dir]);
    }

    int lnGrid = (kROWS + 3) / 4;
    int nxGrid = (kNX + 255) / 256;
    dim3 fcGrid(kG, kT, kB);

    // stage 1: x = x + fconv(x)
    ln_kernel<<<lnGrid, 256, 0, stream>>>(x, bufA, ln1_g, ln1_b, kROWS);
    fconv_kernel<<<fcGrid, 256, 0, stream>>>(bufA, x, xbuf, conv1_w, conv1_b, prelu1);

    // stage 2: x = x + full(x)
    ln_kernel<<<lnGrid, 256, 0, stream>>>(xbuf, bufA, lnf_g, lnf_b, kROWS);
    squeeze_kernel<<<dim3(kB * kT, (kF + 63) / 64), 64, 0, stream>>>(bufA, bufB, sq_w, sq_b);
    fullmat_gemm<<<dim3(5, 4, kS), 256, 0, stream>>>(bufB, bufC, full_w, full_b);
    unsqueeze_kernel<<<nxGrid, 256, 0, stream>>>(bufC, xbuf, unsq_w, unsq_b);

    // stage 3: x = x + fconv(x)  (in-place: resid == out)
    ln_kernel<<<lnGrid, 256, 0, stream>>>(xbuf, bufA, ln2_g, ln2_b, kROWS);
    fconv_kernel<<<fcGrid, 256, 0, stream>>>(bufA, xbuf, xbuf, conv2_w, conv2_b, prelu2);

    // mamba input: xn = LN(x)
    ln_kernel<<<lnGrid, 256, 0, stream>>>(xbuf, xn, lnm_g, lnm_b, kROWS);

    for (int dir = 0; dir < 2; dir++) {
        int wi = 21 + dir * 9;
        const float* conv_w = (const float*)d_in[wi + 1];
        const float* conv_b = (const float*)d_in[wi + 2];
        const float* dt_w   = (const float*)d_in[wi + 4];
        const float* dt_b   = (const float*)d_in[wi + 5];
        const float* A_log  = (const float*)d_in[wi + 6];
        const float* Dp     = (const float*)d_in[wi + 7];

        inproj_gemm<<<dim3((kROWS + 63) / 64, 3), 256, 0, stream>>>(xn, in_wT[dir], bufA, bufB);
        mconv_kernel<<<(kROWS * 48 + 255) / 256, 256, 0, stream>>>(bufA, bufC, conv_w, conv_b, dir);
        xpproj_gemm<<<(kROWS + 63) / 64, 256, 0, stream>>>(bufC, bufA, xp_wp[dir]);
        scan_kernel<<<kBM, kD, 0, stream>>>(bufA, bufC, A_log, dt_w, dt_b, Dp, dir);
        outproj_gemm<<<(kROWS + 63) / 64, 256, 0, stream>>>(bufC, bufB, out_wp[dir], xbuf, (float*)d_out, dir);
    }
}